// Round 9
// baseline (915.682 us; speedup 1.0000x reference)
//
#include <hip/hip_runtime.h>
#include <cstdint>
#include <cstddef>

#define DEVI __device__ __forceinline__

typedef __attribute__((ext_vector_type(8))) short s8v;   // 8 bf16 bit patterns
typedef __attribute__((ext_vector_type(4))) float f4v;

static constexpr int B_ = 4, AT = 48, NBRS = 20;
static constexpr int R2 = B_ * AT * NBRS;   // 3840 (b,i,j) rows
static constexpr int M4 = R2 * NBRS;        // 76800 (b,i,j,k) rows

// ---------------- workspace layout (float offsets) ----------------
static constexpr size_t OFF_B2A  = 0;                          // hi/lo frag-major 512x128
static constexpr size_t OFF_B2B  = OFF_B2A + 524288;           // 128x512
static constexpr size_t OFF_B3A  = OFF_B2B + 524288;           // 640x320 (col-permuted)
static constexpr size_t OFF_BW3B = OFF_B3A + 1638400;          // plain-W hi/lo 128x640 frag-major
static constexpr size_t OFF_BN3B = OFF_BW3B + 81920;           // noise 2^i*n 128x5120 frag-major (single bf16)
static constexpr size_t OFF_W72A = OFF_BN3B + 327680;          // 512x128 f (bit-7 noisy)
static constexpr size_t OFF_W72B = OFF_W72A + 65536;           // 128x512 f
static constexpr size_t OFF_W73A = OFF_W72B + 65536;           // 640x320 f
static constexpr size_t OFF_W73B = OFF_W73A + 204800;          // 128x640 f
static constexpr size_t OFF_RS   = OFF_W73B + 81920;           // 1408: rs2a@0 rs2b@512 rs3a@640 rs3b@1280
static constexpr size_t OFF_SLOT = OFF_RS + 1408;              // 16
static constexpr size_t OFF_BN   = OFF_SLOT + 16;              // 256
static constexpr size_t OFF_C2IN = OFF_BN + 256;               // 3840x128
static constexpr size_t OFF_Z1   = OFF_C2IN + (size_t)R2 * 128;
static constexpr size_t OFF_C2B  = OFF_Z1 + (size_t)R2 * 512;  // (unused now)
static constexpr size_t OFF_Z2   = OFF_C2B + (size_t)R2 * 512;
static constexpr size_t OFF_TWO  = OFF_Z2 + (size_t)R2 * 128;
static constexpr size_t OFF_NK   = OFF_TWO + (size_t)R2 * 64;
static constexpr size_t OFF_P2   = OFF_NK + (size_t)R2 * 64;   // 3840x640 (full P12, node_i folded)
static constexpr size_t OFF_P3   = OFF_P2 + (size_t)R2 * 640;
static constexpr size_t OFF_TSUM = OFF_P3 + (size_t)R2 * 640;
static constexpr size_t OFF_Q2A  = OFF_TSUM + (size_t)R2 * 64; // 3840x128 bytes
static constexpr size_t OFF_Q2B  = OFF_Q2A + 122880;           // 3840x512 bytes
static constexpr size_t OFF_QP2  = OFF_Q2B + 491520;           // 3840x192 bytes
static constexpr size_t OFF_QP3  = OFF_QP2 + 184320;           // 3840x128 bytes

// ---------------- threefry-2x32 (JAX-compatible, verified) ----------------
DEVI void tf2x32(unsigned k0, unsigned k1, unsigned x0, unsigned x1,
                 unsigned& o0, unsigned& o1) {
  unsigned ks0 = k0, ks1 = k1, ks2 = k0 ^ k1 ^ 0x1BD11BDAu;
  x0 += ks0; x1 += ks1;
  const unsigned rotA[4] = {13u, 15u, 26u, 6u};
  const unsigned rotB[4] = {17u, 29u, 16u, 24u};
  unsigned ks[3] = {ks0, ks1, ks2};
  #pragma unroll
  for (int i = 0; i < 5; ++i) {
    const unsigned* rot = (i & 1) ? rotB : rotA;
    #pragma unroll
    for (int r = 0; r < 4; ++r) {
      x0 += x1;
      x1 = (x1 << rot[r]) | (x1 >> (32u - rot[r]));
      x1 ^= x0;
    }
    x0 += ks[(i + 1) % 3];
    x1 += ks[(i + 2) % 3] + (unsigned)(i + 1);
  }
  o0 = x0; o1 = x1;
}

DEVI float erfinv_xla(float x) {
  float w = -log1pf(-x * x);
  float p;
  if (w < 5.f) {
    w -= 2.5f;
    p = 2.81022636e-08f;
    p = fmaf(p, w, 3.43273939e-07f);
    p = fmaf(p, w, -3.5233877e-06f);
    p = fmaf(p, w, -4.39150654e-06f);
    p = fmaf(p, w, 0.00021858087f);
    p = fmaf(p, w, -0.00125372503f);
    p = fmaf(p, w, -0.00417768164f);
    p = fmaf(p, w, 0.246640727f);
    p = fmaf(p, w, 1.50140941f);
  } else {
    w = sqrtf(w) - 3.f;
    p = -0.000200214257f;
    p = fmaf(p, w, 0.000100950558f);
    p = fmaf(p, w, 0.00134934322f);
    p = fmaf(p, w, -0.00367342844f);
    p = fmaf(p, w, 0.00573950773f);
    p = fmaf(p, w, -0.0076224613f);
    p = fmaf(p, w, 0.00943887047f);
    p = fmaf(p, w, 1.00167406f);
    p = fmaf(p, w, 2.83297682f);
  }
  return p * x;
}

DEVI float normal_from_bits(unsigned bits) {
  unsigned fb = (bits >> 9) | 0x3F800000u;
  float f = __uint_as_float(fb) - 1.0f;
  const float lo = -0.99999994f;
  float u = f * (1.0f - lo) + lo;
  u = fmaxf(lo, u);
  return 1.41421356237f * erfinv_xla(u);
}

DEVI unsigned f2o(float f) { unsigned u = __float_as_uint(f); return (u & 0x80000000u) ? ~u : (u | 0x80000000u); }
DEVI float o2f(unsigned u) { return (u & 0x80000000u) ? __uint_as_float(u & 0x7FFFFFFFu) : __uint_as_float(~u); }

DEVI unsigned short f2bf(float x) {  // RNE f32 -> bf16
  unsigned u = __float_as_uint(x);
  return (unsigned short)((u + 0x7FFFu + ((u >> 16) & 1u)) >> 16);
}
DEVI float bf2f(unsigned short h) { return __uint_as_float((unsigned)h << 16); }

DEVI void blockMinMax(float lmn, float lmx, float* smem, unsigned* slot) {
  float* smn = smem; float* smx = smem + 256;
  int t = threadIdx.x;
  smn[t] = lmn; smx[t] = lmx;
  __syncthreads();
  for (int s = 128; s > 0; s >>= 1) {
    if (t < s) { smn[t] = fminf(smn[t], smn[t + s]); smx[t] = fmaxf(smx[t], smx[t + s]); }
    __syncthreads();
  }
  if (t == 0) { atomicMin(slot + 0, f2o(smn[0])); atomicMax(slot + 1, f2o(smx[0])); }
}

// bit-spread expansion: byte b -> 8 bf16 {0,1} in PERMUTED elem order {0,2,1,3,4,6,5,7}
DEVI s8v expand_mul(unsigned b) {
  unsigned sl = (b & 15u) * 0x00204081u;
  unsigned sh = ((b >> 4) & 15u) * 0x00204081u;
  union { unsigned u[4]; s8v s; } r;
  r.u[0] = (sl & 0x00010001u) * 0x3F80u;
  r.u[1] = ((sl >> 8) & 0x00010001u) * 0x3F80u;
  r.u[2] = (sh & 0x00010001u) * 0x3F80u;
  r.u[3] = ((sh >> 8) & 0x00010001u) * 0x3F80u;
  return r.s;
}
// matching store-side permutation (involution: 1<->2, 5<->6)
DEVI int bperm(int bit) { return bit ^ ((((bit) ^ (bit >> 1)) & 1) * 3); }

// 8 q-bytes (two u32) -> 8 bf16 (exact for 0..255), natural order
DEVI s8v bytes_to_bf16(unsigned a, unsigned b) {
  union { unsigned u[4]; s8v s; } r;
  float f0 = (float)(a & 255u), f1 = (float)((a >> 8) & 255u);
  float f2 = (float)((a >> 16) & 255u), f3 = (float)(a >> 24);
  r.u[0] = (__float_as_uint(f0) >> 16) | (__float_as_uint(f1) & 0xFFFF0000u);
  r.u[1] = (__float_as_uint(f2) >> 16) | (__float_as_uint(f3) & 0xFFFF0000u);
  f0 = (float)(b & 255u); f1 = (float)((b >> 8) & 255u);
  f2 = (float)((b >> 16) & 255u); f3 = (float)(b >> 24);
  r.u[2] = (__float_as_uint(f0) >> 16) | (__float_as_uint(f1) & 0xFFFF0000u);
  r.u[3] = (__float_as_uint(f2) >> 16) | (__float_as_uint(f3) & 0xFFFF0000u);
  return r.s;
}

// ---------------- K1: init + all expanded weights ----------------
__global__ __launch_bounds__(256) void k_prep(
    const float* __restrict__ W2A, const float* __restrict__ W2B,
    const float* __restrict__ W3A, const float* __restrict__ W3B,
    short* __restrict__ B2A, short* __restrict__ B2B, short* __restrict__ B3A,
    short* __restrict__ BW3B, short* __restrict__ BN3B,
    float* __restrict__ W72A, float* __restrict__ W72B,
    float* __restrict__ W73A, float* __restrict__ W73B,
    float* __restrict__ z1, float* __restrict__ z2, float* __restrict__ tsum,
    unsigned* __restrict__ slots) {
  int t = blockIdx.x * 256 + threadIdx.x;
  if (t < R2 * 512) z1[t] = 0.f;
  if (t < R2 * 128) z2[t] = 0.f;
  if (t < R2 * 64) tsum[t] = 0.f;
  if (t < 4) { slots[2 * t] = f2o(3.402823466e38f); slots[2 * t + 1] = f2o(-3.402823466e38f); }
  int lt = t;
  const float* W; float* W7; int N, K; unsigned layer; int which;
  if (lt < 524288) { W = W2A; W7 = W72A; N = 512; K = 128; layer = 0u; which = 0; }
  else if ((lt -= 524288) < 524288) { W = W2B; W7 = W72B; N = 128; K = 512; layer = 1u; which = 1; }
  else if ((lt -= 524288) < 1638400) { W = W3A; W7 = W73A; N = 640; K = 320; layer = 2u; which = 2; }
  else if ((lt -= 1638400) < 655360) { W = W3B; W7 = W73B; N = 128; K = 640; layer = 3u; which = 3; }
  else return;
  int n_elem = N * K;
  int bit = lt / n_elem;
  int e = lt - bit * n_elem;
  unsigned kl0, kl1, kb0, kb1, r0, r1;
  tf2x32(0u, 42u, 0u, layer, kl0, kl1);
  tf2x32(kl0, kl1, 0u, (unsigned)bit, kb0, kb1);
  tf2x32(kb0, kb1, 0u, (unsigned)e, r0, r1);
  float w = W[e];
  float nz = normal_from_bits(r0 ^ r1) * fabsf(w) * 0.1f;
  float wn = w + nz;
  int n = e / K, k = e - n * K;
  if (bit == 7) W7[e] = wn;
  if (which == 3) {
    // noise part, single bf16, fragment-major over K'=5120, permuted elem order
    BN3B[((size_t)(n >> 4) * 160 + (size_t)(k >> 2)) * 512
         + (size_t)((k & 3) * 16 + (n & 15)) * 8 + bperm(bit)] = (short)f2bf(ldexpf(nz, bit));
    if (bit == 0) {  // plain W hi/lo, fragment-major over K=640 (natural elem order)
      unsigned short hi = f2bf(w);
      unsigned short lo = f2bf(w - bf2f(hi));
      size_t o2 = (((size_t)(n >> 4) * 20 + (size_t)(k >> 5)) * 2) * 512
                + (size_t)(((k >> 3) & 3) * 16 + (n & 15)) * 8 + (k & 7);
      BW3B[o2] = (short)hi; BW3B[o2 + 512] = (short)lo;
    }
  } else {
    float sv = ldexpf(wn, bit);
    unsigned short hi = f2bf(sv);
    unsigned short lo = f2bf(sv - bf2f(hi));
    int pk = k;
    if (which == 2) {
      if (k >= 128 && k < 192) pk = k + 64;        // node_k -> 192..256
      else if (k >= 192 && k < 256) pk = k - 64;   // edge_ij -> 128..192
    }
    short* Bf = (which == 0) ? B2A : (which == 1 ? B2B : B3A);
    int KG = K >> 2;
    size_t off = (((size_t)(n >> 4) * KG + (size_t)(pk >> 2)) * 2) * 512
               + (size_t)((pk & 3) * 16 + (n & 15)) * 8 + bperm(bit);
    Bf[off] = (short)hi; Bf[off + 512] = (short)lo;
  }
}

// ---------------- K2: c2in build + NK gather + rowsums (+slot0 minmax) ----------------
__global__ __launch_bounds__(256) void k_build2(
    const float* __restrict__ node, const float* __restrict__ mask,
    const int* __restrict__ nidx, float* __restrict__ c2in, float* __restrict__ NK,
    const float* __restrict__ W72A, const float* __restrict__ W72B,
    const float* __restrict__ W73A, const float* __restrict__ W73B,
    float* __restrict__ rs, unsigned* __restrict__ slot) {
  __shared__ float sred[512];
  int idx = blockIdx.x * 256 + threadIdx.x;
  float lmn = 3.4e38f, lmx = -3.4e38f;
  if (idx < R2 * 128) {
    int row = idx >> 7, c = idx & 127;
    float v;
    if (c < 64) v = node[(size_t)(row / 20) * 64 + c];
    else {
      int b = row / 960;
      v = node[(size_t)(b * 48 + nidx[row]) * 64 + (c - 64)] * mask[row];
    }
    c2in[idx] = v; lmn = v; lmx = v;
  } else if (idx < R2 * 192) {
    int i2 = idx - R2 * 128;
    int row = i2 >> 6, c = i2 & 63;
    int b = row / 960;
    NK[i2] = node[(size_t)(b * 48 + nidx[row]) * 64 + c];
  } else if (idx < R2 * 192 + 1408) {
    int o = idx - R2 * 192;
    const float* p; int cols; int dsto;
    if (o < 512) { p = W72A; cols = 128; dsto = o; }
    else if (o < 640) { p = W72B; cols = 512; dsto = o; o -= 512; }
    else if (o < 1280) { p = W73A; cols = 320; dsto = o; o -= 640; }
    else { p = W73B; cols = 640; dsto = o; o -= 1280; }
    const float* rowp = p + (size_t)o * cols;
    float s = 0.f;
    for (int j = 0; j < cols; ++j) s += rowp[j];
    rs[dsto] = s;
  }
  blockMinMax(lmn, lmx, sred, slot);
}

// ---------------- K3: quant2A + piecewise c3 minmax (slot4) ----------------
__global__ __launch_bounds__(256) void k_qm4(
    const float* __restrict__ node, const float* __restrict__ edge,
    const float* __restrict__ c2in, const float* __restrict__ NK,
    const int* __restrict__ nidx, const unsigned* __restrict__ slot0,
    unsigned char* __restrict__ Q2A, unsigned* __restrict__ slot4) {
  __shared__ float sred[512];
  int idx0 = blockIdx.x * 256 + threadIdx.x;
  if (idx0 < R2 * 128) {
    const float mn = o2f(slot0[0]), mx = o2f(slot0[1]);
    float invd = 255.f / (mx - mn);
    Q2A[idx0] = (unsigned char)((c2in[idx0] - mn) * invd);
  }
  const int n0 = 12288, n1 = n0 + 245760, n2 = n1 + 245760, total = n2 + 4915200;
  float lmn = 3.4e38f, lmx = -3.4e38f;
  for (int idx = idx0; idx < total; idx += gridDim.x * 256) {
    float v, v2;
    if (idx < n0) { v = node[idx]; v2 = v; }
    else if (idx < n1) { v = edge[idx - n0]; v2 = v; }
    else if (idx < n2) {
      int j = idx - n1; int r = j >> 6, c = j & 63;
      v = c2in[(size_t)r * 128 + 64 + c]; v2 = v;
    } else {
      int j = idx - n2; int bij = j / 1280, t = j - bij * 1280;
      int b = bij / 960;
      size_t base = (size_t)((b * 48 + nidx[bij]) * 20) * 64 + t;
      v = NK[base]; v2 = edge[base];
    }
    lmn = fminf(lmn, fminf(v, v2)); lmx = fmaxf(lmx, fmaxf(v, v2));
  }
  blockMinMax(lmn, lmx, sred, slot4);
}

// ---------------- generic MFMA bit-serial GEMM (hi/lo layout, 64-row blocks, 1m x 4n waves) ----------------
__global__ __launch_bounds__(256) void k_mfma_gemm(
    const unsigned char* __restrict__ Q, int ldq,
    const short* __restrict__ B, int KGfull, int kg0,
    int M, int Nfull, int KB, float* __restrict__ Z, int accflag) {
  const int tid = threadIdx.x;
  const int lane = tid & 63, w = tid >> 6;
  const int l15 = lane & 15, l4 = lane >> 4;
  const int mbase = blockIdx.y * 64;
  const int nbase = blockIdx.x * 128;
  const int kq0 = blockIdx.z * KB;
  f4v acc[4][2];
  #pragma unroll
  for (int a = 0; a < 4; ++a)
    #pragma unroll
    for (int b = 0; b < 2; ++b) acc[a][b] = f4v{0.f, 0.f, 0.f, 0.f};
  for (int ks16 = 0; ks16 < KB; ks16 += 16) {
    uint4 qv[4];
    #pragma unroll
    for (int mf = 0; mf < 4; ++mf)
      qv[mf] = *(const uint4*)(Q + (size_t)(mbase + mf * 16 + l15) * ldq + kq0 + ks16);
    #pragma unroll
    for (int sub = 0; sub < 4; ++sub) {
      int kg = kg0 + ((kq0 + ks16) >> 2) + sub;
      s8v af[4];
      #pragma unroll
      for (int mf = 0; mf < 4; ++mf) {
        unsigned wv = (sub == 0) ? qv[mf].x : (sub == 1) ? qv[mf].y : (sub == 2) ? qv[mf].z : qv[mf].w;
        af[mf] = expand_mul((wv >> (l4 * 8)) & 255u);
      }
      #pragma unroll
      for (int j = 0; j < 2; ++j) {
        size_t o = (((size_t)(nbase / 16 + w * 2 + j) * KGfull + kg) * 2) * 512 + (size_t)lane * 8;
        s8v bh = *(const s8v*)(B + o);
        s8v bl = *(const s8v*)(B + o + 512);
        #pragma unroll
        for (int mf = 0; mf < 4; ++mf) {
          acc[mf][j] = __builtin_amdgcn_mfma_f32_16x16x32_bf16(af[mf], bh, acc[mf][j], 0, 0, 0);
          acc[mf][j] = __builtin_amdgcn_mfma_f32_16x16x32_bf16(af[mf], bl, acc[mf][j], 0, 0, 0);
        }
      }
    }
  }
  #pragma unroll
  for (int mf = 0; mf < 4; ++mf) {
    #pragma unroll
    for (int r = 0; r < 4; ++r) {
      int m = mbase + mf * 16 + l4 * 4 + r;
      float* zp = Z + (size_t)m * Nfull + nbase;
      #pragma unroll
      for (int j = 0; j < 2; ++j) {
        int n = (w * 2 + j) * 16 + l15;
        if (accflag == 0) zp[n] = acc[mf][j][r];
        else atomicAdd(zp + n, acc[mf][j][r]);
      }
    }
  }
}

// ---------------- K5: act1 minmax only (slot2) ----------------
__global__ __launch_bounds__(256) void k_act1(const float* __restrict__ z1, const float* __restrict__ rs,
                                              const unsigned* __restrict__ slot0,
                                              unsigned* __restrict__ slot1) {
  __shared__ float sred[512];
  const float mn = o2f(slot0[0]), mx = o2f(slot0[1]);
  int idx = blockIdx.x * 256 + threadIdx.x;
  float lmn = 3.4e38f, lmx = -3.4e38f;
  if (idx < R2 * 512) {
    int o = idx & 511;
    float v = fmaxf(0.f, z1[idx] * (1.f / 255.f) * (mx - mn) + mn * rs[o]);
    lmn = v; lmx = v;
  }
  blockMinMax(lmn, lmx, sred, slot1);
}

// ---------------- K6: quant2B (recompute act from z1) + quant3 ----------------
__global__ __launch_bounds__(256) void k_qq(
    const float* __restrict__ z1, const float* __restrict__ rs,
    const float* __restrict__ node, const float* __restrict__ edge,
    const float* __restrict__ c2in, const float* __restrict__ NK,
    const int* __restrict__ nidx, const unsigned* __restrict__ slot0,
    const unsigned* __restrict__ slot2, const unsigned* __restrict__ slot4,
    unsigned char* __restrict__ Q2B, unsigned char* __restrict__ QP2, unsigned char* __restrict__ QP3) {
  int idx = blockIdx.x * 256 + threadIdx.x;
  if (idx < R2 * 512) {
    const float mn0 = o2f(slot0[0]), mx0 = o2f(slot0[1]);
    const float mn = o2f(slot2[0]), mx = o2f(slot2[1]);
    int o = idx & 511;
    float v = fmaxf(0.f, z1[idx] * (1.f / 255.f) * (mx0 - mn0) + mn0 * rs[o]);
    Q2B[idx] = (unsigned char)((v - mn) * (255.f / (mx - mn)));
    return;
  }
  int j = idx - R2 * 512;
  const int seg = 245760;
  if (j >= 5 * seg) return;
  const float mn = o2f(slot4[0]), mx = o2f(slot4[1]);
  const float invd = 255.f / (mx - mn);
  int s = j / seg; int jj = j - s * seg;
  int r = jj >> 6, c = jj & 63;
  float v; unsigned char* dst;
  if (s == 0)      { v = node[(size_t)(r / 20) * 64 + c];  dst = QP2 + (size_t)r * 192 + c; }
  else if (s == 1) { v = c2in[(size_t)r * 128 + 64 + c];   dst = QP2 + (size_t)r * 192 + 64 + c; }
  else if (s == 2) { v = edge[(size_t)r * 64 + c];         dst = QP2 + (size_t)r * 192 + 128 + c; }
  else if (s == 3) { v = NK[(size_t)r * 64 + c];           dst = QP3 + (size_t)r * 128 + c; }
  else             { v = edge[(size_t)r * 64 + c];         dst = QP3 + (size_t)r * 128 + 64 + c; }
  *dst = (unsigned char)((v - mn) * invd);
}

// ---------------- K8: merged P2/P3 GEMM (64-row blocks, 1m x 4n waves) ----------------
__global__ __launch_bounds__(256) void k_mfma_p23(
    const unsigned char* __restrict__ Q2, const unsigned char* __restrict__ Q3,
    const short* __restrict__ B, float* __restrict__ P2, float* __restrict__ P3) {
  const int half = blockIdx.y >= 60;
  const int by = blockIdx.y - half * 60;
  const unsigned char* Q = half ? Q3 : Q2;
  float* Z = half ? P3 : P2;
  const int kg0 = half ? 48 : 0;
  const int KB = half ? 128 : 192;
  const int ldq = half ? 128 : 192;
  const int tid = threadIdx.x;
  const int lane = tid & 63, w = tid >> 6;
  const int l15 = lane & 15, l4 = lane >> 4;
  const int mbase = by * 64;
  const int nbase = blockIdx.x * 128;
  f4v acc[4][2];
  #pragma unroll
  for (int a = 0; a < 4; ++a)
    #pragma unroll
    for (int b = 0; b < 2; ++b) acc[a][b] = f4v{0.f, 0.f, 0.f, 0.f};
  for (int ks16 = 0; ks16 < KB; ks16 += 16) {
    uint4 qv[4];
    #pragma unroll
    for (int mf = 0; mf < 4; ++mf)
      qv[mf] = *(const uint4*)(Q + (size_t)(mbase + mf * 16 + l15) * ldq + ks16);
    #pragma unroll
    for (int sub = 0; sub < 4; ++sub) {
      int kg = kg0 + (ks16 >> 2) + sub;
      s8v af[4];
      #pragma unroll
      for (int mf = 0; mf < 4; ++mf) {
        unsigned wv = (sub == 0) ? qv[mf].x : (sub == 1) ? qv[mf].y : (sub == 2) ? qv[mf].z : qv[mf].w;
        af[mf] = expand_mul((wv >> (l4 * 8)) & 255u);
      }
      #pragma unroll
      for (int j = 0; j < 2; ++j) {
        size_t o = (((size_t)(nbase / 16 + w * 2 + j) * 80 + kg) * 2) * 512 + (size_t)lane * 8;
        s8v bh = *(const s8v*)(B + o);
        s8v bl = *(const s8v*)(B + o + 512);
        #pragma unroll
        for (int mf = 0; mf < 4; ++mf) {
          acc[mf][j] = __builtin_amdgcn_mfma_f32_16x16x32_bf16(af[mf], bh, acc[mf][j], 0, 0, 0);
          acc[mf][j] = __builtin_amdgcn_mfma_f32_16x16x32_bf16(af[mf], bl, acc[mf][j], 0, 0, 0);
        }
      }
    }
  }
  #pragma unroll
  for (int mf = 0; mf < 4; ++mf) {
    #pragma unroll
    for (int r = 0; r < 4; ++r) {
      int m = mbase + mf * 16 + l4 * 4 + r;
      float* zp = Z + (size_t)m * 640 + nbase;
      #pragma unroll
      for (int j = 0; j < 2; ++j)
        zp[(w * 2 + j) * 16 + l15] = acc[mf][j][r];
    }
  }
}

// ---------------- K9: act2 + minmax3 (slot6) ----------------
__global__ __launch_bounds__(256) void k_act2mm3(
    const float* __restrict__ z2, const float* __restrict__ rs2b,
    const unsigned* __restrict__ slot2, float* __restrict__ two,
    const float* __restrict__ P12, const float* __restrict__ P3,
    const float* __restrict__ rs3a, const int* __restrict__ nidx,
    const unsigned* __restrict__ slot4, unsigned* __restrict__ slot6) {
  __shared__ float p12s[640];
  __shared__ float bias[640];
  __shared__ float sred[512];
  int gid = blockIdx.x * 256 + threadIdx.x;
  if (gid < R2 * 64) {
    const float mn = o2f(slot2[0]), mx = o2f(slot2[1]);
    int row = gid >> 6, c = gid & 63;
    float d = (mx - mn) * (1.f / 255.f);
    float g = z2[(size_t)row * 128 + c] * d + mn * rs2b[c];
    float e = z2[(size_t)row * 128 + 64 + c] * d + mn * rs2b[64 + c];
    two[gid] = (1.f / (1.f + expf(-g))) * tanhf(e);
  }
  const int bij = blockIdx.x;
  const int b = bij / 960;
  const int jp = nidx[bij];
  const size_t p3b = (size_t)((b * 48 + jp) * 20) * 640;
  const float mn2 = o2f(slot4[0]), mx2 = o2f(slot4[1]);
  const float sc2 = (mx2 - mn2) * (1.f / 255.f);
  for (int k = threadIdx.x; k < 640; k += 256) {
    p12s[k] = P12[(size_t)bij * 640 + k];
    bias[k] = mn2 * rs3a[k];
  }
  __syncthreads();
  float lmn = 3.4e38f, lmx = -3.4e38f;
  for (int t = threadIdx.x; t < 20 * 640; t += 256) {
    int knb = t / 640, k = t - knb * 640;
    float v = fmaxf(0.f, (p12s[k] + P3[p3b + t]) * sc2 + bias[k]);
    lmn = fminf(lmn, v); lmx = fmaxf(lmx, v);
  }
  blockMinMax(lmn, lmx, sred, slot6);
}

// ---------------- K10: fused 3-body layer 2 — K-SPLIT ACROSS WAVES ----------------
// Wave w: full 64x128 tile over kg in [40w,40w+40), c in [5w,5w+5).
// Expansion redundancy 1x (was 4x), B-dedup preserved. Cross-wave f32 reduce in LDS
// (aliases qt after MFMA), fused epilogue per 16-row chunk.
__global__ __launch_bounds__(256, 2) void k_mfma_l3b(
    const float* __restrict__ P12, const float* __restrict__ P3,
    const float* __restrict__ rs3a, const float* __restrict__ rs3b,
    const short* __restrict__ BW, const short* __restrict__ BN,
    const int* __restrict__ nidx, const float* __restrict__ mask,
    const unsigned* __restrict__ slotA, const unsigned* __restrict__ slotB,
    float* __restrict__ tsum) {
  __shared__ unsigned char qt[64 * 648];   // 41472 B; aliased as zz[4][16][132] f32 after MFMA
  const int tid = threadIdx.x;
  const int s0 = blockIdx.x * 64;
  const float mn2 = o2f(slotA[0]), mx2 = o2f(slotA[1]);
  const float mn3 = o2f(slotB[0]), mx3 = o2f(slotB[1]);
  const float sc2 = (mx2 - mn2) * (1.f / 255.f);
  const float invd3 = 255.f / (mx3 - mn3);
  {
    int r = tid >> 2, kq = (tid & 3) * 160;
    int s = s0 + r;
    int bij = s / 20, knb = s - bij * 20, b = bij / 960;
    int p3row = (b * 48 + nidx[bij]) * 20 + knb;
    const float* pa = P12 + (size_t)bij * 640;
    const float* pb = P3 + (size_t)p3row * 640;
    for (int k = kq; k < kq + 160; k += 4) {
      float4 va = *(const float4*)(pa + k);
      float4 vb = *(const float4*)(pb + k);
      float4 rv = *(const float4*)(rs3a + k);
      float v0 = fmaxf(0.f, (va.x + vb.x) * sc2 + mn2 * rv.x);
      float v1 = fmaxf(0.f, (va.y + vb.y) * sc2 + mn2 * rv.y);
      float v2 = fmaxf(0.f, (va.z + vb.z) * sc2 + mn2 * rv.z);
      float v3 = fmaxf(0.f, (va.w + vb.w) * sc2 + mn2 * rv.w);
      unsigned pk = (unsigned)((v0 - mn3) * invd3) | ((unsigned)((v1 - mn3) * invd3) << 8)
                  | ((unsigned)((v2 - mn3) * invd3) << 16) | ((unsigned)((v3 - mn3) * invd3) << 24);
      *(unsigned*)(&qt[(size_t)r * 648 + k]) = pk;
    }
  }
  __syncthreads();
  const int lane = tid & 63, w = tid >> 6;
  const int l15 = lane & 15, l4 = lane >> 4;
  const unsigned char* qr[4];
  #pragma unroll
  for (int mf = 0; mf < 4; ++mf) qr[mf] = qt + (size_t)(mf * 16 + l15) * 648;
  f4v acc[4][8];
  #pragma unroll
  for (int a = 0; a < 4; ++a)
    #pragma unroll
    for (int b = 0; b < 8; ++b) acc[a][b] = f4v{0.f, 0.f, 0.f, 0.f};
  const int kg0 = w * 40;
  // noise part: depth-1 prefetched 8-stream pipeline over this wave's K-quarter
  s8v cur[8];
  #pragma unroll
  for (int j = 0; j < 8; ++j)
    cur[j] = *(const s8v*)(BN + ((size_t)j * 160 + kg0) * 512 + (size_t)lane * 8);
  for (int kgl = 0; kgl < 40; ++kgl) {
    const int kg = kg0 + kgl;
    s8v af[4];
    #pragma unroll
    for (int mf = 0; mf < 4; ++mf) {
      unsigned wv = *(const unsigned*)(qr[mf] + kg * 4);
      af[mf] = expand_mul((wv >> (l4 * 8)) & 255u);
    }
    s8v nxt[8];
    #pragma unroll
    for (int j = 0; j < 8; ++j)   // last iter of wave 3 reads just past BN (into W72A region): unused
      nxt[j] = *(const s8v*)(BN + ((size_t)j * 160 + kg + 1) * 512 + (size_t)lane * 8);
    #pragma unroll
    for (int j = 0; j < 8; ++j) {
      #pragma unroll
      for (int mf = 0; mf < 4; ++mf)
        acc[mf][j] = __builtin_amdgcn_mfma_f32_16x16x32_bf16(af[mf], cur[j], acc[mf][j], 0, 0, 0);
    }
    #pragma unroll
    for (int j = 0; j < 8; ++j) cur[j] = nxt[j];
  }
  // q-part: this wave's c-range, W hi/lo
  #pragma unroll
  for (int cl = 0; cl < 5; ++cl) {
    const int c = w * 5 + cl;
    s8v aq[4];
    #pragma unroll
    for (int mf = 0; mf < 4; ++mf) {
      unsigned a0 = *(const unsigned*)(qr[mf] + c * 32 + l4 * 8);
      unsigned a1 = *(const unsigned*)(qr[mf] + c * 32 + l4 * 8 + 4);
      aq[mf] = bytes_to_bf16(a0, a1);
    }
    #pragma unroll
    for (int j = 0; j < 8; ++j) {
      s8v bh = *(const s8v*)(BW + (((size_t)j * 20 + c) * 2) * 512 + (size_t)lane * 8);
      s8v bl = *(const s8v*)(BW + (((size_t)j * 20 + c) * 2 + 1) * 512 + (size_t)lane * 8);
      #pragma unroll
      for (int mf = 0; mf < 4; ++mf) {
        acc[mf][j] = __builtin_amdgcn_mfma_f32_16x16x32_bf16(aq[mf], bh, acc[mf][j], 0, 0, 0);
        acc[mf][j] = __builtin_amdgcn_mfma_f32_16x16x32_bf16(aq[mf], bl, acc[mf][j], 0, 0, 0);
      }
    }
  }
  // cross-wave reduce + fused epilogue, per 16-row chunk (zz aliases qt; 4x16x132 f32 = 33792 B)
  float* zz = (float*)qt;
  const float d3 = (mx3 - mn3) * (1.f / 255.f);
  for (int mf = 0; mf < 4; ++mf) {
    __syncthreads();   // prior chunk (or qt) reads complete before overwrite
    #pragma unroll
    for (int j = 0; j < 8; ++j) {
      #pragma unroll
      for (int r = 0; r < 4; ++r)
        zz[((size_t)w * 16 + l4 * 4 + r) * 132 + j * 16 + l15] = acc[mf][j][r];
    }
    __syncthreads();
    #pragma unroll
    for (int k = 0; k < 4; ++k) {
      int o = tid + k * 256;
      int row = o >> 6, cc = o & 63;
      float zg = zz[(size_t)row * 132 + cc] + zz[(size_t)(16 + row) * 132 + cc]
               + zz[(size_t)(32 + row) * 132 + cc] + zz[(size_t)(48 + row) * 132 + cc];
      float ze = zz[(size_t)row * 132 + 64 + cc] + zz[(size_t)(16 + row) * 132 + 64 + cc]
               + zz[(size_t)(32 + row) * 132 + 64 + cc] + zz[(size_t)(48 + row) * 132 + 64 + cc];
      int s = s0 + mf * 16 + row;
      int bij = s / 20, knb = s - bij * 20, b = bij / 960;
      int p3row = (b * 48 + nidx[bij]) * 20 + knb;
      float mk = mask[p3row];
      float g = zg * d3 + mn3 * rs3b[cc];
      float e = ze * d3 + mn3 * rs3b[64 + cc];
      float val = (1.f / (1.f + expf(-g))) * tanhf(e) * mk;
      atomicAdd(&tsum[(size_t)bij * 64 + cc], val);
    }
  }
}

// ---------------- K11/K12: BN stats + final ----------------
__global__ __launch_bounds__(256) void k_bnstats2(const float* __restrict__ two, const float* __restrict__ tsum,
                                                  float* __restrict__ bn) {
  __shared__ float ss[512];
  const float* x = blockIdx.y ? tsum : two;
  float* mout = bn + (blockIdx.y ? 128 : 0);
  float* vout = mout + 64;
  int c = blockIdx.x, t = threadIdx.x;
  float s = 0.f, q = 0.f;
  for (int r = t; r < R2; r += 256) { float v = x[(size_t)r * 64 + c]; s += v; q += v * v; }
  ss[t] = s; ss[256 + t] = q;
  __syncthreads();
  for (int st = 128; st > 0; st >>= 1) {
    if (t < st) { ss[t] += ss[t + st]; ss[256 + t] += ss[256 + t + st]; }
    __syncthreads();
  }
  if (t == 0) { float m = ss[0] / (float)R2; mout[c] = m; vout[c] = ss[256] / (float)R2 - m * m; }
}

__global__ __launch_bounds__(256) void k_final(const float* __restrict__ edge, const float* __restrict__ two,
                                               const float* __restrict__ tsum, const float* __restrict__ bn,
                                               const float* __restrict__ g2, const float* __restrict__ b2,
                                               const float* __restrict__ g3, const float* __restrict__ b3,
                                               float* __restrict__ out) {
  int idx = blockIdx.x * 256 + threadIdx.x;
  if (idx >= R2 * 64) return;
  int c = idx & 63;
  float t2 = (two[idx] - bn[c]) / sqrtf(bn[64 + c] + 1e-5f) * g2[c] + b2[c];
  float t3 = (tsum[idx] - bn[128 + c]) / sqrtf(bn[192 + c] + 1e-5f) * g3[c] + b3[c];
  out[idx] = fmaxf(0.f, edge[idx] + t2 + t3);
}

// ---------------- host launcher ----------------
extern "C" void kernel_launch(void* const* d_in, const int* in_sizes, int n_in,
                              void* d_out, int out_size, void* d_ws, size_t ws_size,
                              hipStream_t stream) {
  (void)in_sizes; (void)n_in; (void)out_size; (void)ws_size;
  const float* node   = (const float*)d_in[0];
  const float* edge   = (const float*)d_in[1];
  const float* mask   = (const float*)d_in[2];
  const float* c_two  = (const float*)d_in[3];
  const float* c_two2 = (const float*)d_in[4];
  const float* c_three  = (const float*)d_in[5];
  const float* c_three2 = (const float*)d_in[6];
  const float* bn2g = (const float*)d_in[7];
  const float* bn2b = (const float*)d_in[8];
  const float* bn3g = (const float*)d_in[9];
  const float* bn3b = (const float*)d_in[10];
  const int*   nidx = (const int*)d_in[11];
  float* ws = (float*)d_ws;
  unsigned* slots = (unsigned*)(ws + OFF_SLOT);
  float* out = (float*)d_out;
  short* B2A  = (short*)(ws + OFF_B2A);
  short* B2B  = (short*)(ws + OFF_B2B);
  short* B3A  = (short*)(ws + OFF_B3A);
  short* BW3B = (short*)(ws + OFF_BW3B);
  short* BN3B = (short*)(ws + OFF_BN3B);
  unsigned char* Q2A = (unsigned char*)(ws + OFF_Q2A);
  unsigned char* Q2B = (unsigned char*)(ws + OFF_Q2B);
  unsigned char* QP2 = (unsigned char*)(ws + OFF_QP2);
  unsigned char* QP3 = (unsigned char*)(ws + OFF_QP3);
  float* RS = ws + OFF_RS;

  // K1: init + expanded weights
  k_prep<<<13056, 256, 0, stream>>>(c_two, c_two2, c_three, c_three2,
                                    B2A, B2B, B3A, BW3B, BN3B,
                                    ws + OFF_W72A, ws + OFF_W72B, ws + OFF_W73A, ws + OFF_W73B,
                                    ws + OFF_Z1, ws + OFF_Z2, ws + OFF_TSUM, slots);
  // K2: build c2in/NK + rowsums + slot0
  k_build2<<<2886, 256, 0, stream>>>(node, mask, nidx, ws + OFF_C2IN, ws + OFF_NK,
                                     ws + OFF_W72A, ws + OFF_W72B, ws + OFF_W73A, ws + OFF_W73B,
                                     RS, slots + 0);
  // K3: quant2A + 3-body minmax (slot4)
  k_qm4<<<2048, 256, 0, stream>>>(node, edge, ws + OFF_C2IN, ws + OFF_NK, nidx, slots + 0,
                                  Q2A, slots + 4);
  // K4: 2-body layer 1 (64-row tiles, z=2)
  k_mfma_gemm<<<dim3(4, 60, 2), 256, 0, stream>>>(Q2A, 128, B2A, 32, 0, 3840, 512, 64, ws + OFF_Z1, 3);
  // K5: act1 minmax (slot2)
  k_act1<<<7680, 256, 0, stream>>>(ws + OFF_Z1, RS, slots + 0, slots + 2);
  // K6: quant2B (from z1) + quant3
  k_qq<<<12480, 256, 0, stream>>>(ws + OFF_Z1, RS, node, edge, ws + OFF_C2IN, ws + OFF_NK,
                                  nidx, slots + 0, slots + 2, slots + 4, Q2B, QP2, QP3);
  // K7: 2-body layer 2 (64-row tiles, z=4)
  k_mfma_gemm<<<dim3(1, 60, 4), 256, 0, stream>>>(Q2B, 512, B2B, 128, 0, 3840, 128, 128, ws + OFF_Z2, 3);
  // K8: merged P2 (incl node_i) / P3 (64-row tiles)
  k_mfma_p23<<<dim3(5, 120), 256, 0, stream>>>(QP2, QP3, B3A, ws + OFF_P2, ws + OFF_P3);
  // K9: act2 + minmax3 (slot6)
  k_act2mm3<<<3840, 256, 0, stream>>>(ws + OFF_Z2, RS + 512, slots + 2, ws + OFF_TWO,
                                      ws + OFF_P2, ws + OFF_P3, RS + 640, nidx, slots + 4, slots + 6);
  // K10: fused 3-body layer 2 (K-split waves)
  k_mfma_l3b<<<1200, 256, 0, stream>>>(ws + OFF_P2, ws + OFF_P3, RS + 640, RS + 1280,
                                       BW3B, BN3B, nidx, mask, slots + 4, slots + 6, ws + OFF_TSUM);
  // K11/K12
  k_bnstats2<<<dim3(64, 2), 256, 0, stream>>>(ws + OFF_TWO, ws + OFF_TSUM, ws + OFF_BN);
  k_final<<<960, 256, 0, stream>>>(edge, ws + OFF_TWO, ws + OFF_TSUM, ws + OFF_BN,
                                   bn2g, bn2b, bn3g, bn3b, out);
}

// Round 10
// 807.648 us; speedup vs baseline: 1.1338x; 1.1338x over previous
//
#include <hip/hip_runtime.h>
#include <cstdint>
#include <cstddef>

#define DEVI __device__ __forceinline__

typedef __attribute__((ext_vector_type(8))) short s8v;   // 8 bf16 bit patterns
typedef __attribute__((ext_vector_type(4))) float f4v;

static constexpr int B_ = 4, AT = 48, NBRS = 20;
static constexpr int R2 = B_ * AT * NBRS;   // 3840 (b,i,j) rows
static constexpr int M4 = R2 * NBRS;        // 76800 (b,i,j,k) rows

// ---------------- workspace layout (float offsets) ----------------
static constexpr size_t OFF_B2A  = 0;                          // hi/lo frag-major 512x128
static constexpr size_t OFF_B2B  = OFF_B2A + 524288;           // 128x512
static constexpr size_t OFF_B3A  = OFF_B2B + 524288;           // 640x320 (col-permuted)
static constexpr size_t OFF_BW3B = OFF_B3A + 1638400;          // plain-W hi/lo 128x640 frag-major
static constexpr size_t OFF_BN3B = OFF_BW3B + 81920;           // noise 2^i*n 128x5120 frag-major (single bf16)
static constexpr size_t OFF_W72A = OFF_BN3B + 327680;          // 512x128 f (bit-7 noisy)
static constexpr size_t OFF_W72B = OFF_W72A + 65536;           // 128x512 f
static constexpr size_t OFF_W73A = OFF_W72B + 65536;           // 640x320 f
static constexpr size_t OFF_W73B = OFF_W73A + 204800;          // 128x640 f
static constexpr size_t OFF_RS   = OFF_W73B + 81920;           // 1408: rs2a@0 rs2b@512 rs3a@640 rs3b@1280
static constexpr size_t OFF_SLOT = OFF_RS + 1408;              // 16
static constexpr size_t OFF_BN   = OFF_SLOT + 16;              // 256
static constexpr size_t OFF_C2IN = OFF_BN + 256;               // 3840x128
static constexpr size_t OFF_Z1   = OFF_C2IN + (size_t)R2 * 128;
static constexpr size_t OFF_C2B  = OFF_Z1 + (size_t)R2 * 512;  // (unused now)
static constexpr size_t OFF_Z2   = OFF_C2B + (size_t)R2 * 512;
static constexpr size_t OFF_TWO  = OFF_Z2 + (size_t)R2 * 128;
static constexpr size_t OFF_NK   = OFF_TWO + (size_t)R2 * 64;
static constexpr size_t OFF_P2   = OFF_NK + (size_t)R2 * 64;   // 3840x640 (full P12, node_i folded)
static constexpr size_t OFF_P3   = OFF_P2 + (size_t)R2 * 640;
static constexpr size_t OFF_TSUM = OFF_P3 + (size_t)R2 * 640;
static constexpr size_t OFF_Q2A  = OFF_TSUM + (size_t)R2 * 64; // 3840x128 bytes
static constexpr size_t OFF_Q2B  = OFF_Q2A + 122880;           // 3840x512 bytes
static constexpr size_t OFF_QP2  = OFF_Q2B + 491520;           // 3840x192 bytes
static constexpr size_t OFF_QP3  = OFF_QP2 + 184320;           // 3840x128 bytes

// ---------------- threefry-2x32 (JAX-compatible, verified) ----------------
DEVI void tf2x32(unsigned k0, unsigned k1, unsigned x0, unsigned x1,
                 unsigned& o0, unsigned& o1) {
  unsigned ks0 = k0, ks1 = k1, ks2 = k0 ^ k1 ^ 0x1BD11BDAu;
  x0 += ks0; x1 += ks1;
  const unsigned rotA[4] = {13u, 15u, 26u, 6u};
  const unsigned rotB[4] = {17u, 29u, 16u, 24u};
  unsigned ks[3] = {ks0, ks1, ks2};
  #pragma unroll
  for (int i = 0; i < 5; ++i) {
    const unsigned* rot = (i & 1) ? rotB : rotA;
    #pragma unroll
    for (int r = 0; r < 4; ++r) {
      x0 += x1;
      x1 = (x1 << rot[r]) | (x1 >> (32u - rot[r]));
      x1 ^= x0;
    }
    x0 += ks[(i + 1) % 3];
    x1 += ks[(i + 2) % 3] + (unsigned)(i + 1);
  }
  o0 = x0; o1 = x1;
}

DEVI float erfinv_xla(float x) {
  float w = -log1pf(-x * x);
  float p;
  if (w < 5.f) {
    w -= 2.5f;
    p = 2.81022636e-08f;
    p = fmaf(p, w, 3.43273939e-07f);
    p = fmaf(p, w, -3.5233877e-06f);
    p = fmaf(p, w, -4.39150654e-06f);
    p = fmaf(p, w, 0.00021858087f);
    p = fmaf(p, w, -0.00125372503f);
    p = fmaf(p, w, -0.00417768164f);
    p = fmaf(p, w, 0.246640727f);
    p = fmaf(p, w, 1.50140941f);
  } else {
    w = sqrtf(w) - 3.f;
    p = -0.000200214257f;
    p = fmaf(p, w, 0.000100950558f);
    p = fmaf(p, w, 0.00134934322f);
    p = fmaf(p, w, -0.00367342844f);
    p = fmaf(p, w, 0.00573950773f);
    p = fmaf(p, w, -0.0076224613f);
    p = fmaf(p, w, 0.00943887047f);
    p = fmaf(p, w, 1.00167406f);
    p = fmaf(p, w, 2.83297682f);
  }
  return p * x;
}

DEVI float normal_from_bits(unsigned bits) {
  unsigned fb = (bits >> 9) | 0x3F800000u;
  float f = __uint_as_float(fb) - 1.0f;
  const float lo = -0.99999994f;
  float u = f * (1.0f - lo) + lo;
  u = fmaxf(lo, u);
  return 1.41421356237f * erfinv_xla(u);
}

DEVI unsigned f2o(float f) { unsigned u = __float_as_uint(f); return (u & 0x80000000u) ? ~u : (u | 0x80000000u); }
DEVI float o2f(unsigned u) { return (u & 0x80000000u) ? __uint_as_float(u & 0x7FFFFFFFu) : __uint_as_float(~u); }

DEVI unsigned short f2bf(float x) {  // RNE f32 -> bf16
  unsigned u = __float_as_uint(x);
  return (unsigned short)((u + 0x7FFFu + ((u >> 16) & 1u)) >> 16);
}
DEVI float bf2f(unsigned short h) { return __uint_as_float((unsigned)h << 16); }

DEVI void blockMinMax(float lmn, float lmx, float* smem, unsigned* slot) {
  float* smn = smem; float* smx = smem + 256;
  int t = threadIdx.x;
  smn[t] = lmn; smx[t] = lmx;
  __syncthreads();
  for (int s = 128; s > 0; s >>= 1) {
    if (t < s) { smn[t] = fminf(smn[t], smn[t + s]); smx[t] = fmaxf(smx[t], smx[t + s]); }
    __syncthreads();
  }
  if (t == 0) { atomicMin(slot + 0, f2o(smn[0])); atomicMax(slot + 1, f2o(smx[0])); }
}

// bit-spread expansion: byte b -> 8 bf16 {0,1} in PERMUTED elem order {0,2,1,3,4,6,5,7}
DEVI s8v expand_mul(unsigned b) {
  unsigned sl = (b & 15u) * 0x00204081u;
  unsigned sh = ((b >> 4) & 15u) * 0x00204081u;
  union { unsigned u[4]; s8v s; } r;
  r.u[0] = (sl & 0x00010001u) * 0x3F80u;
  r.u[1] = ((sl >> 8) & 0x00010001u) * 0x3F80u;
  r.u[2] = (sh & 0x00010001u) * 0x3F80u;
  r.u[3] = ((sh >> 8) & 0x00010001u) * 0x3F80u;
  return r.s;
}
// matching store-side permutation (involution: 1<->2, 5<->6)
DEVI constexpr int bperm(int bit) { return bit ^ ((((bit) ^ (bit >> 1)) & 1) * 3); }

// 8 q-bytes (two u32) -> 8 bf16 (exact for 0..255), natural order
DEVI s8v bytes_to_bf16(unsigned a, unsigned b) {
  union { unsigned u[4]; s8v s; } r;
  float f0 = (float)(a & 255u), f1 = (float)((a >> 8) & 255u);
  float f2 = (float)((a >> 16) & 255u), f3 = (float)(a >> 24);
  r.u[0] = (__float_as_uint(f0) >> 16) | (__float_as_uint(f1) & 0xFFFF0000u);
  r.u[1] = (__float_as_uint(f2) >> 16) | (__float_as_uint(f3) & 0xFFFF0000u);
  f0 = (float)(b & 255u); f1 = (float)((b >> 8) & 255u);
  f2 = (float)((b >> 16) & 255u); f3 = (float)(b >> 24);
  r.u[2] = (__float_as_uint(f0) >> 16) | (__float_as_uint(f1) & 0xFFFF0000u);
  r.u[3] = (__float_as_uint(f2) >> 16) | (__float_as_uint(f3) & 0xFFFF0000u);
  return r.s;
}

// ---------------- K1: init + all expanded weights (thread-per-element, 16B stores) ----------------
__global__ __launch_bounds__(256) void k_prep(
    const float* __restrict__ W2A, const float* __restrict__ W2B,
    const float* __restrict__ W3A, const float* __restrict__ W3B,
    short* __restrict__ B2A, short* __restrict__ B2B, short* __restrict__ B3A,
    short* __restrict__ BW3B, short* __restrict__ BN3B,
    float* __restrict__ W72A, float* __restrict__ W72B,
    float* __restrict__ W73A, float* __restrict__ W73B,
    float* __restrict__ z1, float* __restrict__ z2, float* __restrict__ tsum,
    unsigned* __restrict__ slots) {
  int t = blockIdx.x * 256 + threadIdx.x;
  if (t < R2 * 512) z1[t] = 0.f;
  if (t < R2 * 128) z2[t] = 0.f;
  if (t < R2 * 64) tsum[t] = 0.f;
  if (t < 4) { slots[2 * t] = f2o(3.402823466e38f); slots[2 * t + 1] = f2o(-3.402823466e38f); }
  int lt = t;
  const float* W; float* W7; int N, K; unsigned layer; int which;
  if (lt < 65536) { W = W2A; W7 = W72A; N = 512; K = 128; layer = 0u; which = 0; }
  else if ((lt -= 65536) < 65536) { W = W2B; W7 = W72B; N = 128; K = 512; layer = 1u; which = 1; }
  else if ((lt -= 65536) < 204800) { W = W3A; W7 = W73A; N = 640; K = 320; layer = 2u; which = 2; }
  else if ((lt -= 204800) < 81920) { W = W3B; W7 = W73B; N = 128; K = 640; layer = 3u; which = 3; }
  else return;
  int e = lt;
  int n = e / K, k = e - n * K;
  float w = W[e];
  float aw = fabsf(w) * 0.1f;
  unsigned kl0, kl1;
  tf2x32(0u, 42u, 0u, layer, kl0, kl1);
  union { short s[8]; s8v v; } hv, lv, bnv;
  #pragma unroll
  for (int bit = 0; bit < 8; ++bit) {
    unsigned kb0, kb1, r0, r1;
    tf2x32(kl0, kl1, 0u, (unsigned)bit, kb0, kb1);
    tf2x32(kb0, kb1, 0u, (unsigned)e, r0, r1);
    float nz = normal_from_bits(r0 ^ r1) * aw;
    float wn = w + nz;
    if (bit == 7) W7[e] = wn;
    if (which == 3) {
      bnv.s[bperm(bit)] = (short)f2bf(ldexpf(nz, bit));
    } else {
      float sv = ldexpf(wn, bit);
      unsigned short hi = f2bf(sv);
      unsigned short lo = f2bf(sv - bf2f(hi));
      hv.s[bperm(bit)] = (short)hi;
      lv.s[bperm(bit)] = (short)lo;
    }
  }
  if (which == 3) {
    *(s8v*)(BN3B + ((size_t)(n >> 4) * 160 + (size_t)(k >> 2)) * 512
                 + (size_t)((k & 3) * 16 + (n & 15)) * 8) = bnv.v;
    unsigned short hi = f2bf(w);
    unsigned short lo = f2bf(w - bf2f(hi));
    size_t o2 = (((size_t)(n >> 4) * 20 + (size_t)(k >> 5)) * 2) * 512
              + (size_t)(((k >> 3) & 3) * 16 + (n & 15)) * 8 + (k & 7);
    BW3B[o2] = (short)hi; BW3B[o2 + 512] = (short)lo;
  } else {
    int pk = k;
    if (which == 2) {
      if (k >= 128 && k < 192) pk = k + 64;        // node_k -> 192..256
      else if (k >= 192 && k < 256) pk = k - 64;   // edge_ij -> 128..192
    }
    short* Bf = (which == 0) ? B2A : (which == 1 ? B2B : B3A);
    int KG = K >> 2;
    size_t off = (((size_t)(n >> 4) * KG + (size_t)(pk >> 2)) * 2) * 512
               + (size_t)((pk & 3) * 16 + (n & 15)) * 8;
    *(s8v*)(Bf + off) = hv.v;
    *(s8v*)(Bf + off + 512) = lv.v;
  }
}

// ---------------- K2: c2in build + NK gather + rowsums (+slot0 minmax) ----------------
__global__ __launch_bounds__(256) void k_build2(
    const float* __restrict__ node, const float* __restrict__ mask,
    const int* __restrict__ nidx, float* __restrict__ c2in, float* __restrict__ NK,
    const float* __restrict__ W72A, const float* __restrict__ W72B,
    const float* __restrict__ W73A, const float* __restrict__ W73B,
    float* __restrict__ rs, unsigned* __restrict__ slot) {
  __shared__ float sred[512];
  int idx = blockIdx.x * 256 + threadIdx.x;
  float lmn = 3.4e38f, lmx = -3.4e38f;
  if (idx < R2 * 128) {
    int row = idx >> 7, c = idx & 127;
    float v;
    if (c < 64) v = node[(size_t)(row / 20) * 64 + c];
    else {
      int b = row / 960;
      v = node[(size_t)(b * 48 + nidx[row]) * 64 + (c - 64)] * mask[row];
    }
    c2in[idx] = v; lmn = v; lmx = v;
  } else if (idx < R2 * 192) {
    int i2 = idx - R2 * 128;
    int row = i2 >> 6, c = i2 & 63;
    int b = row / 960;
    NK[i2] = node[(size_t)(b * 48 + nidx[row]) * 64 + c];
  } else if (idx < R2 * 192 + 1408) {
    int o = idx - R2 * 192;
    const float* p; int cols; int dsto;
    if (o < 512) { p = W72A; cols = 128; dsto = o; }
    else if (o < 640) { p = W72B; cols = 512; dsto = o; o -= 512; }
    else if (o < 1280) { p = W73A; cols = 320; dsto = o; o -= 640; }
    else { p = W73B; cols = 640; dsto = o; o -= 1280; }
    const float* rowp = p + (size_t)o * cols;
    float s = 0.f;
    for (int j = 0; j < cols; ++j) s += rowp[j];
    rs[dsto] = s;
  }
  blockMinMax(lmn, lmx, sred, slot);
}

// ---------------- K3: quant2A + piecewise c3 minmax (slot4) ----------------
__global__ __launch_bounds__(256) void k_qm4(
    const float* __restrict__ node, const float* __restrict__ edge,
    const float* __restrict__ c2in, const float* __restrict__ NK,
    const int* __restrict__ nidx, const unsigned* __restrict__ slot0,
    unsigned char* __restrict__ Q2A, unsigned* __restrict__ slot4) {
  __shared__ float sred[512];
  int idx0 = blockIdx.x * 256 + threadIdx.x;
  if (idx0 < R2 * 128) {
    const float mn = o2f(slot0[0]), mx = o2f(slot0[1]);
    float invd = 255.f / (mx - mn);
    Q2A[idx0] = (unsigned char)((c2in[idx0] - mn) * invd);
  }
  const int n0 = 12288, n1 = n0 + 245760, n2 = n1 + 245760, total = n2 + 4915200;
  float lmn = 3.4e38f, lmx = -3.4e38f;
  for (int idx = idx0; idx < total; idx += gridDim.x * 256) {
    float v, v2;
    if (idx < n0) { v = node[idx]; v2 = v; }
    else if (idx < n1) { v = edge[idx - n0]; v2 = v; }
    else if (idx < n2) {
      int j = idx - n1; int r = j >> 6, c = j & 63;
      v = c2in[(size_t)r * 128 + 64 + c]; v2 = v;
    } else {
      int j = idx - n2; int bij = j / 1280, t = j - bij * 1280;
      int b = bij / 960;
      size_t base = (size_t)((b * 48 + nidx[bij]) * 20) * 64 + t;
      v = NK[base]; v2 = edge[base];
    }
    lmn = fminf(lmn, fminf(v, v2)); lmx = fmaxf(lmx, fmaxf(v, v2));
  }
  blockMinMax(lmn, lmx, sred, slot4);
}

// ---------------- generic MFMA bit-serial GEMM (hi/lo layout, 64-row blocks, 1m x 4n waves) ----------------
__global__ __launch_bounds__(256) void k_mfma_gemm(
    const unsigned char* __restrict__ Q, int ldq,
    const short* __restrict__ B, int KGfull, int kg0,
    int M, int Nfull, int KB, float* __restrict__ Z, int accflag) {
  const int tid = threadIdx.x;
  const int lane = tid & 63, w = tid >> 6;
  const int l15 = lane & 15, l4 = lane >> 4;
  const int mbase = blockIdx.y * 64;
  const int nbase = blockIdx.x * 128;
  const int kq0 = blockIdx.z * KB;
  f4v acc[4][2];
  #pragma unroll
  for (int a = 0; a < 4; ++a)
    #pragma unroll
    for (int b = 0; b < 2; ++b) acc[a][b] = f4v{0.f, 0.f, 0.f, 0.f};
  for (int ks16 = 0; ks16 < KB; ks16 += 16) {
    uint4 qv[4];
    #pragma unroll
    for (int mf = 0; mf < 4; ++mf)
      qv[mf] = *(const uint4*)(Q + (size_t)(mbase + mf * 16 + l15) * ldq + kq0 + ks16);
    #pragma unroll
    for (int sub = 0; sub < 4; ++sub) {
      int kg = kg0 + ((kq0 + ks16) >> 2) + sub;
      s8v af[4];
      #pragma unroll
      for (int mf = 0; mf < 4; ++mf) {
        unsigned wv = (sub == 0) ? qv[mf].x : (sub == 1) ? qv[mf].y : (sub == 2) ? qv[mf].z : qv[mf].w;
        af[mf] = expand_mul((wv >> (l4 * 8)) & 255u);
      }
      #pragma unroll
      for (int j = 0; j < 2; ++j) {
        size_t o = (((size_t)(nbase / 16 + w * 2 + j) * KGfull + kg) * 2) * 512 + (size_t)lane * 8;
        s8v bh = *(const s8v*)(B + o);
        s8v bl = *(const s8v*)(B + o + 512);
        #pragma unroll
        for (int mf = 0; mf < 4; ++mf) {
          acc[mf][j] = __builtin_amdgcn_mfma_f32_16x16x32_bf16(af[mf], bh, acc[mf][j], 0, 0, 0);
          acc[mf][j] = __builtin_amdgcn_mfma_f32_16x16x32_bf16(af[mf], bl, acc[mf][j], 0, 0, 0);
        }
      }
    }
  }
  #pragma unroll
  for (int mf = 0; mf < 4; ++mf) {
    #pragma unroll
    for (int r = 0; r < 4; ++r) {
      int m = mbase + mf * 16 + l4 * 4 + r;
      float* zp = Z + (size_t)m * Nfull + nbase;
      #pragma unroll
      for (int j = 0; j < 2; ++j) {
        int n = (w * 2 + j) * 16 + l15;
        if (accflag == 0) zp[n] = acc[mf][j][r];
        else atomicAdd(zp + n, acc[mf][j][r]);
      }
    }
  }
}

// ---------------- K5: act1 minmax only (slot2) ----------------
__global__ __launch_bounds__(256) void k_act1(const float* __restrict__ z1, const float* __restrict__ rs,
                                              const unsigned* __restrict__ slot0,
                                              unsigned* __restrict__ slot1) {
  __shared__ float sred[512];
  const float mn = o2f(slot0[0]), mx = o2f(slot0[1]);
  int idx = blockIdx.x * 256 + threadIdx.x;
  float lmn = 3.4e38f, lmx = -3.4e38f;
  if (idx < R2 * 512) {
    int o = idx & 511;
    float v = fmaxf(0.f, z1[idx] * (1.f / 255.f) * (mx - mn) + mn * rs[o]);
    lmn = v; lmx = v;
  }
  blockMinMax(lmn, lmx, sred, slot1);
}

// ---------------- K6: quant2B (recompute act from z1) + quant3 ----------------
__global__ __launch_bounds__(256) void k_qq(
    const float* __restrict__ z1, const float* __restrict__ rs,
    const float* __restrict__ node, const float* __restrict__ edge,
    const float* __restrict__ c2in, const float* __restrict__ NK,
    const int* __restrict__ nidx, const unsigned* __restrict__ slot0,
    const unsigned* __restrict__ slot2, const unsigned* __restrict__ slot4,
    unsigned char* __restrict__ Q2B, unsigned char* __restrict__ QP2, unsigned char* __restrict__ QP3) {
  int idx = blockIdx.x * 256 + threadIdx.x;
  if (idx < R2 * 512) {
    const float mn0 = o2f(slot0[0]), mx0 = o2f(slot0[1]);
    const float mn = o2f(slot2[0]), mx = o2f(slot2[1]);
    int o = idx & 511;
    float v = fmaxf(0.f, z1[idx] * (1.f / 255.f) * (mx0 - mn0) + mn0 * rs[o]);
    Q2B[idx] = (unsigned char)((v - mn) * (255.f / (mx - mn)));
    return;
  }
  int j = idx - R2 * 512;
  const int seg = 245760;
  if (j >= 5 * seg) return;
  const float mn = o2f(slot4[0]), mx = o2f(slot4[1]);
  const float invd = 255.f / (mx - mn);
  int s = j / seg; int jj = j - s * seg;
  int r = jj >> 6, c = jj & 63;
  float v; unsigned char* dst;
  if (s == 0)      { v = node[(size_t)(r / 20) * 64 + c];  dst = QP2 + (size_t)r * 192 + c; }
  else if (s == 1) { v = c2in[(size_t)r * 128 + 64 + c];   dst = QP2 + (size_t)r * 192 + 64 + c; }
  else if (s == 2) { v = edge[(size_t)r * 64 + c];         dst = QP2 + (size_t)r * 192 + 128 + c; }
  else if (s == 3) { v = NK[(size_t)r * 64 + c];           dst = QP3 + (size_t)r * 128 + c; }
  else             { v = edge[(size_t)r * 64 + c];         dst = QP3 + (size_t)r * 128 + 64 + c; }
  *dst = (unsigned char)((v - mn) * invd);
}

// ---------------- K8: merged P2/P3 GEMM (64-row blocks, 1m x 4n waves) ----------------
__global__ __launch_bounds__(256) void k_mfma_p23(
    const unsigned char* __restrict__ Q2, const unsigned char* __restrict__ Q3,
    const short* __restrict__ B, float* __restrict__ P2, float* __restrict__ P3) {
  const int half = blockIdx.y >= 60;
  const int by = blockIdx.y - half * 60;
  const unsigned char* Q = half ? Q3 : Q2;
  float* Z = half ? P3 : P2;
  const int kg0 = half ? 48 : 0;
  const int KB = half ? 128 : 192;
  const int ldq = half ? 128 : 192;
  const int tid = threadIdx.x;
  const int lane = tid & 63, w = tid >> 6;
  const int l15 = lane & 15, l4 = lane >> 4;
  const int mbase = by * 64;
  const int nbase = blockIdx.x * 128;
  f4v acc[4][2];
  #pragma unroll
  for (int a = 0; a < 4; ++a)
    #pragma unroll
    for (int b = 0; b < 2; ++b) acc[a][b] = f4v{0.f, 0.f, 0.f, 0.f};
  for (int ks16 = 0; ks16 < KB; ks16 += 16) {
    uint4 qv[4];
    #pragma unroll
    for (int mf = 0; mf < 4; ++mf)
      qv[mf] = *(const uint4*)(Q + (size_t)(mbase + mf * 16 + l15) * ldq + ks16);
    #pragma unroll
    for (int sub = 0; sub < 4; ++sub) {
      int kg = kg0 + (ks16 >> 2) + sub;
      s8v af[4];
      #pragma unroll
      for (int mf = 0; mf < 4; ++mf) {
        unsigned wv = (sub == 0) ? qv[mf].x : (sub == 1) ? qv[mf].y : (sub == 2) ? qv[mf].z : qv[mf].w;
        af[mf] = expand_mul((wv >> (l4 * 8)) & 255u);
      }
      #pragma unroll
      for (int j = 0; j < 2; ++j) {
        size_t o = (((size_t)(nbase / 16 + w * 2 + j) * 80 + kg) * 2) * 512 + (size_t)lane * 8;
        s8v bh = *(const s8v*)(B + o);
        s8v bl = *(const s8v*)(B + o + 512);
        #pragma unroll
        for (int mf = 0; mf < 4; ++mf) {
          acc[mf][j] = __builtin_amdgcn_mfma_f32_16x16x32_bf16(af[mf], bh, acc[mf][j], 0, 0, 0);
          acc[mf][j] = __builtin_amdgcn_mfma_f32_16x16x32_bf16(af[mf], bl, acc[mf][j], 0, 0, 0);
        }
      }
    }
  }
  #pragma unroll
  for (int mf = 0; mf < 4; ++mf) {
    #pragma unroll
    for (int r = 0; r < 4; ++r) {
      int m = mbase + mf * 16 + l4 * 4 + r;
      float* zp = Z + (size_t)m * 640 + nbase;
      #pragma unroll
      for (int j = 0; j < 2; ++j)
        zp[(w * 2 + j) * 16 + l15] = acc[mf][j][r];
    }
  }
}

// ---------------- K9: act2 + minmax3 (slot6) ----------------
__global__ __launch_bounds__(256) void k_act2mm3(
    const float* __restrict__ z2, const float* __restrict__ rs2b,
    const unsigned* __restrict__ slot2, float* __restrict__ two,
    const float* __restrict__ P12, const float* __restrict__ P3,
    const float* __restrict__ rs3a, const int* __restrict__ nidx,
    const unsigned* __restrict__ slot4, unsigned* __restrict__ slot6) {
  __shared__ float p12s[640];
  __shared__ float bias[640];
  __shared__ float sred[512];
  int gid = blockIdx.x * 256 + threadIdx.x;
  if (gid < R2 * 64) {
    const float mn = o2f(slot2[0]), mx = o2f(slot2[1]);
    int row = gid >> 6, c = gid & 63;
    float d = (mx - mn) * (1.f / 255.f);
    float g = z2[(size_t)row * 128 + c] * d + mn * rs2b[c];
    float e = z2[(size_t)row * 128 + 64 + c] * d + mn * rs2b[64 + c];
    two[gid] = (1.f / (1.f + expf(-g))) * tanhf(e);
  }
  const int bij = blockIdx.x;
  const int b = bij / 960;
  const int jp = nidx[bij];
  const size_t p3b = (size_t)((b * 48 + jp) * 20) * 640;
  const float mn2 = o2f(slot4[0]), mx2 = o2f(slot4[1]);
  const float sc2 = (mx2 - mn2) * (1.f / 255.f);
  for (int k = threadIdx.x; k < 640; k += 256) {
    p12s[k] = P12[(size_t)bij * 640 + k];
    bias[k] = mn2 * rs3a[k];
  }
  __syncthreads();
  float lmn = 3.4e38f, lmx = -3.4e38f;
  for (int t = threadIdx.x; t < 20 * 640; t += 256) {
    int knb = t / 640, k = t - knb * 640;
    float v = fmaxf(0.f, (p12s[k] + P3[p3b + t]) * sc2 + bias[k]);
    lmn = fminf(lmn, v); lmx = fmaxf(lmx, v);
  }
  blockMinMax(lmn, lmx, sred, slot6);
}

// ---------------- K10: fused 3-body layer 2 (round-6 schedule + setprio) ----------------
// 64-row blocks, 2m x 2n waves, 648-pad LDS, depth-2 BN prefetch, BW-hi prefetch per c.
__global__ __launch_bounds__(256) void k_mfma_l3b(
    const float* __restrict__ P12, const float* __restrict__ P3,
    const float* __restrict__ rs3a, const float* __restrict__ rs3b,
    const short* __restrict__ BW, const short* __restrict__ BN,
    const int* __restrict__ nidx, const float* __restrict__ mask,
    const unsigned* __restrict__ slotA, const unsigned* __restrict__ slotB,
    float* __restrict__ tsum) {
  __shared__ unsigned char qt[64 * 648];   // 648-byte pad: stride 162 words = 2 mod 32 -> conflict-free
  const int tid = threadIdx.x;
  const int s0 = blockIdx.x * 64;
  const float mn2 = o2f(slotA[0]), mx2 = o2f(slotA[1]);
  const float mn3 = o2f(slotB[0]), mx3 = o2f(slotB[1]);
  const float sc2 = (mx2 - mn2) * (1.f / 255.f);
  const float invd3 = 255.f / (mx3 - mn3);
  {
    int r = tid >> 2, kq = (tid & 3) * 160;
    int s = s0 + r;
    int bij = s / 20, knb = s - bij * 20, b = bij / 960;
    int p3row = (b * 48 + nidx[bij]) * 20 + knb;
    const float* pa = P12 + (size_t)bij * 640;
    const float* pb = P3 + (size_t)p3row * 640;
    for (int k = kq; k < kq + 160; k += 4) {
      float4 va = *(const float4*)(pa + k);
      float4 vb = *(const float4*)(pb + k);
      float4 rv = *(const float4*)(rs3a + k);
      float v0 = fmaxf(0.f, (va.x + vb.x) * sc2 + mn2 * rv.x);
      float v1 = fmaxf(0.f, (va.y + vb.y) * sc2 + mn2 * rv.y);
      float v2 = fmaxf(0.f, (va.z + vb.z) * sc2 + mn2 * rv.z);
      float v3 = fmaxf(0.f, (va.w + vb.w) * sc2 + mn2 * rv.w);
      unsigned pk = (unsigned)((v0 - mn3) * invd3) | ((unsigned)((v1 - mn3) * invd3) << 8)
                  | ((unsigned)((v2 - mn3) * invd3) << 16) | ((unsigned)((v3 - mn3) * invd3) << 24);
      *(unsigned*)(&qt[(size_t)r * 648 + k]) = pk;
    }
  }
  __syncthreads();
  const int lane = tid & 63, wave = tid >> 6;
  const int wm = wave >> 1, wn = wave & 1;
  const int l15 = lane & 15, l4 = lane >> 4;
  const int nfl[4] = {2 * wn, 2 * wn + 1, 2 * wn + 4, 2 * wn + 5};
  size_t bb[4];
  #pragma unroll
  for (int j = 0; j < 4; ++j) bb[j] = ((size_t)nfl[j] * 160) * 512 + (size_t)lane * 8;
  f4v acc[2][4];
  #pragma unroll
  for (int a = 0; a < 2; ++a)
    #pragma unroll
    for (int b = 0; b < 4; ++b) acc[a][b] = f4v{0.f, 0.f, 0.f, 0.f};
  // depth-2 BN pipeline
  s8v c0[4], c1[4];
  #pragma unroll
  for (int j = 0; j < 4; ++j) {
    c0[j] = *(const s8v*)(BN + bb[j]);
    c1[j] = *(const s8v*)(BN + bb[j] + 512);
  }
  const unsigned char* qrow0 = &qt[(size_t)(wm * 32 + l15) * 648];
  const unsigned char* qrow1 = qrow0 + 16 * 648;
  for (int c = 0; c < 20; ++c) {
    s8v bwh[4];
    #pragma unroll
    for (int j = 0; j < 4; ++j)   // prefetch q-part hi weights for this c
      bwh[j] = *(const s8v*)(BW + (((size_t)nfl[j] * 20 + c) * 2) * 512 + (size_t)lane * 8);
    #pragma unroll
    for (int s = 0; s < 8; ++s) {
      const int kg = c * 8 + s;
      unsigned w0 = *(const unsigned*)(qrow0 + kg * 4);
      unsigned w1 = *(const unsigned*)(qrow1 + kg * 4);
      s8v af0 = expand_mul((w0 >> (l4 * 8)) & 255u);
      s8v af1 = expand_mul((w1 >> (l4 * 8)) & 255u);
      s8v nx[4];
      #pragma unroll
      for (int j = 0; j < 4; ++j)   // depth-2 prefetch (last iters read past BN into W72A region: unused)
        nx[j] = *(const s8v*)(BN + bb[j] + (size_t)(kg + 2) * 512);
      __builtin_amdgcn_s_setprio(1);
      #pragma unroll
      for (int j = 0; j < 4; ++j) {
        acc[0][j] = __builtin_amdgcn_mfma_f32_16x16x32_bf16(af0, c0[j], acc[0][j], 0, 0, 0);
        acc[1][j] = __builtin_amdgcn_mfma_f32_16x16x32_bf16(af1, c0[j], acc[1][j], 0, 0, 0);
      }
      __builtin_amdgcn_s_setprio(0);
      #pragma unroll
      for (int j = 0; j < 4; ++j) { c0[j] = c1[j]; c1[j] = nx[j]; }
    }
    // q-part for this c (K=32, W hi/lo)
    {
      const int x = c * 32 + l4 * 8;
      unsigned a0 = *(const unsigned*)(qrow0 + x);
      unsigned a1 = *(const unsigned*)(qrow0 + x + 4);
      s8v aq0 = bytes_to_bf16(a0, a1);
      a0 = *(const unsigned*)(qrow1 + x);
      a1 = *(const unsigned*)(qrow1 + x + 4);
      s8v aq1 = bytes_to_bf16(a0, a1);
      __builtin_amdgcn_s_setprio(1);
      #pragma unroll
      for (int j = 0; j < 4; ++j) {
        acc[0][j] = __builtin_amdgcn_mfma_f32_16x16x32_bf16(aq0, bwh[j], acc[0][j], 0, 0, 0);
        acc[1][j] = __builtin_amdgcn_mfma_f32_16x16x32_bf16(aq1, bwh[j], acc[1][j], 0, 0, 0);
        s8v bwl = *(const s8v*)(BW + ((((size_t)nfl[j] * 20 + c) * 2) + 1) * 512 + (size_t)lane * 8);
        acc[0][j] = __builtin_amdgcn_mfma_f32_16x16x32_bf16(aq0, bwl, acc[0][j], 0, 0, 0);
        acc[1][j] = __builtin_amdgcn_mfma_f32_16x16x32_bf16(aq1, bwl, acc[1][j], 0, 0, 0);
      }
      __builtin_amdgcn_s_setprio(0);
    }
  }
  const float d3 = (mx3 - mn3) * (1.f / 255.f);
  float rg[2], re[2];
  #pragma unroll
  for (int j = 0; j < 2; ++j) {
    int gcol = (2 * wn + j) * 16 + l15;
    rg[j] = mn3 * rs3b[gcol];
    re[j] = mn3 * rs3b[64 + gcol];
  }
  #pragma unroll
  for (int mf = 0; mf < 2; ++mf) {
    #pragma unroll
    for (int r = 0; r < 4; ++r) {
      int s = s0 + wm * 32 + mf * 16 + l4 * 4 + r;
      int bij = s / 20, knb = s - bij * 20, b = bij / 960;
      int p3row = (b * 48 + nidx[bij]) * 20 + knb;
      float mk = mask[p3row];
      #pragma unroll
      for (int j = 0; j < 2; ++j) {
        float g = acc[mf][j][r] * d3 + rg[j];
        float e = acc[mf][j + 2][r] * d3 + re[j];
        float val = (1.f / (1.f + expf(-g))) * tanhf(e) * mk;
        atomicAdd(&tsum[(size_t)bij * 64 + (2 * wn + j) * 16 + l15], val);
      }
    }
  }
}

// ---------------- K11/K12: BN stats + final ----------------
__global__ __launch_bounds__(256) void k_bnstats2(const float* __restrict__ two, const float* __restrict__ tsum,
                                                  float* __restrict__ bn) {
  __shared__ float ss[512];
  const float* x = blockIdx.y ? tsum : two;
  float* mout = bn + (blockIdx.y ? 128 : 0);
  float* vout = mout + 64;
  int c = blockIdx.x, t = threadIdx.x;
  float s = 0.f, q = 0.f;
  for (int r = t; r < R2; r += 256) { float v = x[(size_t)r * 64 + c]; s += v; q += v * v; }
  ss[t] = s; ss[256 + t] = q;
  __syncthreads();
  for (int st = 128; st > 0; st >>= 1) {
    if (t < st) { ss[t] += ss[t + st]; ss[256 + t] += ss[256 + t + st]; }
    __syncthreads();
  }
  if (t == 0) { float m = ss[0] / (float)R2; mout[c] = m; vout[c] = ss[256] / (float)R2 - m * m; }
}

__global__ __launch_bounds__(256) void k_final(const float* __restrict__ edge, const float* __restrict__ two,
                                               const float* __restrict__ tsum, const float* __restrict__ bn,
                                               const float* __restrict__ g2, const float* __restrict__ b2,
                                               const float* __restrict__ g3, const float* __restrict__ b3,
                                               float* __restrict__ out) {
  int idx = blockIdx.x * 256 + threadIdx.x;
  if (idx >= R2 * 64) return;
  int c = idx & 63;
  float t2 = (two[idx] - bn[c]) / sqrtf(bn[64 + c] + 1e-5f) * g2[c] + b2[c];
  float t3 = (tsum[idx] - bn[128 + c]) / sqrtf(bn[192 + c] + 1e-5f) * g3[c] + b3[c];
  out[idx] = fmaxf(0.f, edge[idx] + t2 + t3);
}

// ---------------- host launcher ----------------
extern "C" void kernel_launch(void* const* d_in, const int* in_sizes, int n_in,
                              void* d_out, int out_size, void* d_ws, size_t ws_size,
                              hipStream_t stream) {
  (void)in_sizes; (void)n_in; (void)out_size; (void)ws_size;
  const float* node   = (const float*)d_in[0];
  const float* edge   = (const float*)d_in[1];
  const float* mask   = (const float*)d_in[2];
  const float* c_two  = (const float*)d_in[3];
  const float* c_two2 = (const float*)d_in[4];
  const float* c_three  = (const float*)d_in[5];
  const float* c_three2 = (const float*)d_in[6];
  const float* bn2g = (const float*)d_in[7];
  const float* bn2b = (const float*)d_in[8];
  const float* bn3g = (const float*)d_in[9];
  const float* bn3b = (const float*)d_in[10];
  const int*   nidx = (const int*)d_in[11];
  float* ws = (float*)d_ws;
  unsigned* slots = (unsigned*)(ws + OFF_SLOT);
  float* out = (float*)d_out;
  short* B2A  = (short*)(ws + OFF_B2A);
  short* B2B  = (short*)(ws + OFF_B2B);
  short* B3A  = (short*)(ws + OFF_B3A);
  short* BW3B = (short*)(ws + OFF_BW3B);
  short* BN3B = (short*)(ws + OFF_BN3B);
  unsigned char* Q2A = (unsigned char*)(ws + OFF_Q2A);
  unsigned char* Q2B = (unsigned char*)(ws + OFF_Q2B);
  unsigned char* QP2 = (unsigned char*)(ws + OFF_QP2);
  unsigned char* QP3 = (unsigned char*)(ws + OFF_QP3);
  float* RS = ws + OFF_RS;

  // K1: init + expanded weights (thread-per-element)
  k_prep<<<7680, 256, 0, stream>>>(c_two, c_two2, c_three, c_three2,
                                   B2A, B2B, B3A, BW3B, BN3B,
                                   ws + OFF_W72A, ws + OFF_W72B, ws + OFF_W73A, ws + OFF_W73B,
                                   ws + OFF_Z1, ws + OFF_Z2, ws + OFF_TSUM, slots);
  // K2: build c2in/NK + rowsums + slot0
  k_build2<<<2886, 256, 0, stream>>>(node, mask, nidx, ws + OFF_C2IN, ws + OFF_NK,
                                     ws + OFF_W72A, ws + OFF_W72B, ws + OFF_W73A, ws + OFF_W73B,
                                     RS, slots + 0);
  // K3: quant2A + 3-body minmax (slot4)
  k_qm4<<<2048, 256, 0, stream>>>(node, edge, ws + OFF_C2IN, ws + OFF_NK, nidx, slots + 0,
                                  Q2A, slots + 4);
  // K4: 2-body layer 1 (64-row tiles, z=2)
  k_mfma_gemm<<<dim3(4, 60, 2), 256, 0, stream>>>(Q2A, 128, B2A, 32, 0, 3840, 512, 64, ws + OFF_Z1, 3);
  // K5: act1 minmax (slot2)
  k_act1<<<7680, 256, 0, stream>>>(ws + OFF_Z1, RS, slots + 0, slots + 2);
  // K6: quant2B (from z1) + quant3
  k_qq<<<12480, 256, 0, stream>>>(ws + OFF_Z1, RS, node, edge, ws + OFF_C2IN, ws + OFF_NK,
                                  nidx, slots + 0, slots + 2, slots + 4, Q2B, QP2, QP3);
  // K7: 2-body layer 2 (64-row tiles, z=4)
  k_mfma_gemm<<<dim3(1, 60, 4), 256, 0, stream>>>(Q2B, 512, B2B, 128, 0, 3840, 128, 128, ws + OFF_Z2, 3);
  // K8: merged P2 (incl node_i) / P3 (64-row tiles)
  k_mfma_p23<<<dim3(5, 120), 256, 0, stream>>>(QP2, QP3, B3A, ws + OFF_P2, ws + OFF_P3);
  // K9: act2 + minmax3 (slot6)
  k_act2mm3<<<3840, 256, 0, stream>>>(ws + OFF_Z2, RS + 512, slots + 2, ws + OFF_TWO,
                                      ws + OFF_P2, ws + OFF_P3, RS + 640, nidx, slots + 4, slots + 6);
  // K10: fused 3-body layer 2 (round-6 schedule + setprio)
  k_mfma_l3b<<<1200, 256, 0, stream>>>(ws + OFF_P2, ws + OFF_P3, RS + 640, RS + 1280,
                                       BW3B, BN3B, nidx, mask, slots + 4, slots + 6, ws + OFF_TSUM);
  // K11/K12
  k_bnstats2<<<dim3(64, 2), 256, 0, stream>>>(ws + OFF_TWO, ws + OFF_TSUM, ws + OFF_BN);
  k_final<<<960, 256, 0, stream>>>(edge, ws + OFF_TWO, ws + OFF_TSUM, ws + OFF_BN,
                                   bn2g, bn2b, bn3g, bn3b, out);
}

// Round 11
// 798.755 us; speedup vs baseline: 1.1464x; 1.0111x over previous
//
#include <hip/hip_runtime.h>
#include <cstdint>
#include <cstddef>

#define DEVI __device__ __forceinline__

typedef __attribute__((ext_vector_type(8))) short s8v;   // 8 bf16 bit patterns
typedef __attribute__((ext_vector_type(4))) float f4v;

static constexpr int B_ = 4, AT = 48, NBRS = 20;
static constexpr int R2 = B_ * AT * NBRS;   // 3840 (b,i,j) rows
static constexpr int M4 = R2 * NBRS;        // 76800 (b,i,j,k) rows

// ---------------- workspace layout (float offsets) ----------------
// per-layer: BN = noise 2^i*n_i, single bf16, frag-major over K'=8K; BW = plain W hi/lo frag-major over K
static constexpr size_t OFF_BN2A = 0;                          // 512x128:  262144
static constexpr size_t OFF_BW2A = OFF_BN2A + 262144;          // 65536
static constexpr size_t OFF_BN2B = OFF_BW2A + 65536;           // 128x512:  262144
static constexpr size_t OFF_BW2B = OFF_BN2B + 262144;          // 65536
static constexpr size_t OFF_BN3A = OFF_BW2B + 65536;           // 640x320:  819200 (col-permuted)
static constexpr size_t OFF_BW3A = OFF_BN3A + 819200;          // 204800
static constexpr size_t OFF_BN3B = OFF_BW3A + 204800;          // 128x640:  327680
static constexpr size_t OFF_BW3B = OFF_BN3B + 327680;          // 81920
static constexpr size_t OFF_W72A = OFF_BW3B + 81920;           // 512x128 f (bit-7 noisy)
static constexpr size_t OFF_W72B = OFF_W72A + 65536;           // 128x512 f
static constexpr size_t OFF_W73A = OFF_W72B + 65536;           // 640x320 f
static constexpr size_t OFF_W73B = OFF_W73A + 204800;          // 128x640 f
static constexpr size_t OFF_RS   = OFF_W73B + 81920;           // 1408
static constexpr size_t OFF_SLOT = OFF_RS + 1408;              // 16
static constexpr size_t OFF_BN   = OFF_SLOT + 16;              // 256
static constexpr size_t OFF_C2IN = OFF_BN + 256;               // 3840x128
static constexpr size_t OFF_Z1   = OFF_C2IN + (size_t)R2 * 128;
static constexpr size_t OFF_Z2   = OFF_Z1 + (size_t)R2 * 512;
static constexpr size_t OFF_TWO  = OFF_Z2 + (size_t)R2 * 128;
static constexpr size_t OFF_NK   = OFF_TWO + (size_t)R2 * 64;
static constexpr size_t OFF_P2   = OFF_NK + (size_t)R2 * 64;   // 3840x640
static constexpr size_t OFF_P3   = OFF_P2 + (size_t)R2 * 640;
static constexpr size_t OFF_TSUM = OFF_P3 + (size_t)R2 * 640;
static constexpr size_t OFF_Q2A  = OFF_TSUM + (size_t)R2 * 64; // 3840x128 bytes
static constexpr size_t OFF_Q2B  = OFF_Q2A + 122880;           // 3840x512 bytes
static constexpr size_t OFF_QP2  = OFF_Q2B + 491520;           // 3840x192 bytes
static constexpr size_t OFF_QP3  = OFF_QP2 + 184320;           // 3840x128 bytes

// ---------------- threefry-2x32 (JAX-compatible, verified) ----------------
DEVI void tf2x32(unsigned k0, unsigned k1, unsigned x0, unsigned x1,
                 unsigned& o0, unsigned& o1) {
  unsigned ks0 = k0, ks1 = k1, ks2 = k0 ^ k1 ^ 0x1BD11BDAu;
  x0 += ks0; x1 += ks1;
  const unsigned rotA[4] = {13u, 15u, 26u, 6u};
  const unsigned rotB[4] = {17u, 29u, 16u, 24u};
  unsigned ks[3] = {ks0, ks1, ks2};
  #pragma unroll
  for (int i = 0; i < 5; ++i) {
    const unsigned* rot = (i & 1) ? rotB : rotA;
    #pragma unroll
    for (int r = 0; r < 4; ++r) {
      x0 += x1;
      x1 = (x1 << rot[r]) | (x1 >> (32u - rot[r]));
      x1 ^= x0;
    }
    x0 += ks[(i + 1) % 3];
    x1 += ks[(i + 2) % 3] + (unsigned)(i + 1);
  }
  o0 = x0; o1 = x1;
}

DEVI float erfinv_xla(float x) {
  float w = -log1pf(-x * x);
  float p;
  if (w < 5.f) {
    w -= 2.5f;
    p = 2.81022636e-08f;
    p = fmaf(p, w, 3.43273939e-07f);
    p = fmaf(p, w, -3.5233877e-06f);
    p = fmaf(p, w, -4.39150654e-06f);
    p = fmaf(p, w, 0.00021858087f);
    p = fmaf(p, w, -0.00125372503f);
    p = fmaf(p, w, -0.00417768164f);
    p = fmaf(p, w, 0.246640727f);
    p = fmaf(p, w, 1.50140941f);
  } else {
    w = sqrtf(w) - 3.f;
    p = -0.000200214257f;
    p = fmaf(p, w, 0.000100950558f);
    p = fmaf(p, w, 0.00134934322f);
    p = fmaf(p, w, -0.00367342844f);
    p = fmaf(p, w, 0.00573950773f);
    p = fmaf(p, w, -0.0076224613f);
    p = fmaf(p, w, 0.00943887047f);
    p = fmaf(p, w, 1.00167406f);
    p = fmaf(p, w, 2.83297682f);
  }
  return p * x;
}

DEVI float normal_from_bits(unsigned bits) {
  unsigned fb = (bits >> 9) | 0x3F800000u;
  float f = __uint_as_float(fb) - 1.0f;
  const float lo = -0.99999994f;
  float u = f * (1.0f - lo) + lo;
  u = fmaxf(lo, u);
  return 1.41421356237f * erfinv_xla(u);
}

DEVI unsigned f2o(float f) { unsigned u = __float_as_uint(f); return (u & 0x80000000u) ? ~u : (u | 0x80000000u); }
DEVI float o2f(unsigned u) { return (u & 0x80000000u) ? __uint_as_float(u & 0x7FFFFFFFu) : __uint_as_float(~u); }

DEVI unsigned short f2bf(float x) {  // RNE f32 -> bf16
  unsigned u = __float_as_uint(x);
  return (unsigned short)((u + 0x7FFFu + ((u >> 16) & 1u)) >> 16);
}
DEVI float bf2f(unsigned short h) { return __uint_as_float((unsigned)h << 16); }

DEVI void blockMinMax(float lmn, float lmx, float* smem, unsigned* slot) {
  float* smn = smem; float* smx = smem + 256;
  int t = threadIdx.x;
  smn[t] = lmn; smx[t] = lmx;
  __syncthreads();
  for (int s = 128; s > 0; s >>= 1) {
    if (t < s) { smn[t] = fminf(smn[t], smn[t + s]); smx[t] = fmaxf(smx[t], smx[t + s]); }
    __syncthreads();
  }
  if (t == 0) { atomicMin(slot + 0, f2o(smn[0])); atomicMax(slot + 1, f2o(smx[0])); }
}

// bit-spread expansion: byte b -> 8 bf16 {0,1} in PERMUTED elem order {0,2,1,3,4,6,5,7}
DEVI s8v expand_mul(unsigned b) {
  unsigned sl = (b & 15u) * 0x00204081u;
  unsigned sh = ((b >> 4) & 15u) * 0x00204081u;
  union { unsigned u[4]; s8v s; } r;
  r.u[0] = (sl & 0x00010001u) * 0x3F80u;
  r.u[1] = ((sl >> 8) & 0x00010001u) * 0x3F80u;
  r.u[2] = (sh & 0x00010001u) * 0x3F80u;
  r.u[3] = ((sh >> 8) & 0x00010001u) * 0x3F80u;
  return r.s;
}
// matching store-side permutation (involution: 1<->2, 5<->6)
DEVI constexpr int bperm(int bit) { return bit ^ ((((bit) ^ (bit >> 1)) & 1) * 3); }

// 8 q-bytes (two u32) -> 8 bf16 (exact for 0..255), natural order
DEVI s8v bytes_to_bf16(unsigned a, unsigned b) {
  union { unsigned u[4]; s8v s; } r;
  float f0 = (float)(a & 255u), f1 = (float)((a >> 8) & 255u);
  float f2 = (float)((a >> 16) & 255u), f3 = (float)(a >> 24);
  r.u[0] = (__float_as_uint(f0) >> 16) | (__float_as_uint(f1) & 0xFFFF0000u);
  r.u[1] = (__float_as_uint(f2) >> 16) | (__float_as_uint(f3) & 0xFFFF0000u);
  f0 = (float)(b & 255u); f1 = (float)((b >> 8) & 255u);
  f2 = (float)((b >> 16) & 255u); f3 = (float)(b >> 24);
  r.u[2] = (__float_as_uint(f0) >> 16) | (__float_as_uint(f1) & 0xFFFF0000u);
  r.u[3] = (__float_as_uint(f2) >> 16) | (__float_as_uint(f3) & 0xFFFF0000u);
  return r.s;
}

// ---------------- K1: init + all expanded weights (uniform noise-split: BN + BW per layer) ----------------
__global__ __launch_bounds__(256) void k_prep(
    const float* __restrict__ W2A, const float* __restrict__ W2B,
    const float* __restrict__ W3A, const float* __restrict__ W3B,
    short* __restrict__ BN2A, short* __restrict__ BW2A,
    short* __restrict__ BN2B, short* __restrict__ BW2B,
    short* __restrict__ BN3A, short* __restrict__ BW3A,
    short* __restrict__ BN3B, short* __restrict__ BW3B,
    float* __restrict__ W72A, float* __restrict__ W72B,
    float* __restrict__ W73A, float* __restrict__ W73B,
    float* __restrict__ z1, float* __restrict__ z2, float* __restrict__ tsum,
    unsigned* __restrict__ slots) {
  int t = blockIdx.x * 256 + threadIdx.x;
  if (t < R2 * 512) z1[t] = 0.f;
  if (t < R2 * 128) z2[t] = 0.f;
  if (t < R2 * 64) tsum[t] = 0.f;
  if (t < 4) { slots[2 * t] = f2o(3.402823466e38f); slots[2 * t + 1] = f2o(-3.402823466e38f); }
  int lt = t;
  const float* W; float* W7; short* BNp; short* BWp; int K; unsigned layer; int which;
  if (lt < 65536) { W = W2A; W7 = W72A; BNp = BN2A; BWp = BW2A; K = 128; layer = 0u; which = 0; }
  else if ((lt -= 65536) < 65536) { W = W2B; W7 = W72B; BNp = BN2B; BWp = BW2B; K = 512; layer = 1u; which = 1; }
  else if ((lt -= 65536) < 204800) { W = W3A; W7 = W73A; BNp = BN3A; BWp = BW3A; K = 320; layer = 2u; which = 2; }
  else if ((lt -= 204800) < 81920) { W = W3B; W7 = W73B; BNp = BN3B; BWp = BW3B; K = 640; layer = 3u; which = 3; }
  else return;
  int e = lt;
  int n = e / K, k = e - n * K;
  float w = W[e];
  float aw = fabsf(w) * 0.1f;
  unsigned kl0, kl1;
  tf2x32(0u, 42u, 0u, layer, kl0, kl1);
  union { short s[8]; s8v v; } bnv;
  #pragma unroll
  for (int bit = 0; bit < 8; ++bit) {
    unsigned kb0, kb1, r0, r1;
    tf2x32(kl0, kl1, 0u, (unsigned)bit, kb0, kb1);
    tf2x32(kb0, kb1, 0u, (unsigned)e, r0, r1);
    float nz = normal_from_bits(r0 ^ r1) * aw;
    if (bit == 7) W7[e] = w + nz;
    bnv.s[bperm(bit)] = (short)f2bf(ldexpf(nz, bit));
  }
  int pk = k;
  if (which == 2) {
    if (k >= 128 && k < 192) pk = k + 64;        // node_k -> 192..256
    else if (k >= 192 && k < 256) pk = k - 64;   // edge_ij -> 128..192
  }
  // noise fragment-major over K'=8K: kg = pk>>2
  *(s8v*)(BNp + ((size_t)(n >> 4) * (K >> 2) + (size_t)(pk >> 2)) * 512
              + (size_t)((pk & 3) * 16 + (n & 15)) * 8) = bnv.v;
  // plain-W hi/lo fragment-major over K (natural elem order)
  unsigned short hi = f2bf(w);
  unsigned short lo = f2bf(w - bf2f(hi));
  size_t o2 = (((size_t)(n >> 4) * (K >> 5) + (size_t)(pk >> 5)) * 2) * 512
            + (size_t)(((pk >> 3) & 3) * 16 + (n & 15)) * 8 + (pk & 7);
  BWp[o2] = (short)hi; BWp[o2 + 512] = (short)lo;
}

// ---------------- K2: c2in build + NK gather + rowsums (+slot0 minmax) ----------------
__global__ __launch_bounds__(256) void k_build2(
    const float* __restrict__ node, const float* __restrict__ mask,
    const int* __restrict__ nidx, float* __restrict__ c2in, float* __restrict__ NK,
    const float* __restrict__ W72A, const float* __restrict__ W72B,
    const float* __restrict__ W73A, const float* __restrict__ W73B,
    float* __restrict__ rs, unsigned* __restrict__ slot) {
  __shared__ float sred[512];
  int idx = blockIdx.x * 256 + threadIdx.x;
  float lmn = 3.4e38f, lmx = -3.4e38f;
  if (idx < R2 * 128) {
    int row = idx >> 7, c = idx & 127;
    float v;
    if (c < 64) v = node[(size_t)(row / 20) * 64 + c];
    else {
      int b = row / 960;
      v = node[(size_t)(b * 48 + nidx[row]) * 64 + (c - 64)] * mask[row];
    }
    c2in[idx] = v; lmn = v; lmx = v;
  } else if (idx < R2 * 192) {
    int i2 = idx - R2 * 128;
    int row = i2 >> 6, c = i2 & 63;
    int b = row / 960;
    NK[i2] = node[(size_t)(b * 48 + nidx[row]) * 64 + c];
  } else if (idx < R2 * 192 + 1408) {
    int o = idx - R2 * 192;
    const float* p; int cols; int dsto;
    if (o < 512) { p = W72A; cols = 128; dsto = o; }
    else if (o < 640) { p = W72B; cols = 512; dsto = o; o -= 512; }
    else if (o < 1280) { p = W73A; cols = 320; dsto = o; o -= 640; }
    else { p = W73B; cols = 640; dsto = o; o -= 1280; }
    const float* rowp = p + (size_t)o * cols;
    float s = 0.f;
    for (int j = 0; j < cols; ++j) s += rowp[j];
    rs[dsto] = s;
  }
  blockMinMax(lmn, lmx, sred, slot);
}

// ---------------- K3: quant2A + piecewise c3 minmax (slot4) ----------------
__global__ __launch_bounds__(256) void k_qm4(
    const float* __restrict__ node, const float* __restrict__ edge,
    const float* __restrict__ c2in, const float* __restrict__ NK,
    const int* __restrict__ nidx, const unsigned* __restrict__ slot0,
    unsigned char* __restrict__ Q2A, unsigned* __restrict__ slot4) {
  __shared__ float sred[512];
  int idx0 = blockIdx.x * 256 + threadIdx.x;
  if (idx0 < R2 * 128) {
    const float mn = o2f(slot0[0]), mx = o2f(slot0[1]);
    float invd = 255.f / (mx - mn);
    Q2A[idx0] = (unsigned char)((c2in[idx0] - mn) * invd);
  }
  const int n0 = 12288, n1 = n0 + 245760, n2 = n1 + 245760, total = n2 + 4915200;
  float lmn = 3.4e38f, lmx = -3.4e38f;
  for (int idx = idx0; idx < total; idx += gridDim.x * 256) {
    float v, v2;
    if (idx < n0) { v = node[idx]; v2 = v; }
    else if (idx < n1) { v = edge[idx - n0]; v2 = v; }
    else if (idx < n2) {
      int j = idx - n1; int r = j >> 6, c = j & 63;
      v = c2in[(size_t)r * 128 + 64 + c]; v2 = v;
    } else {
      int j = idx - n2; int bij = j / 1280, t = j - bij * 1280;
      int b = bij / 960;
      size_t base = (size_t)((b * 48 + nidx[bij]) * 20) * 64 + t;
      v = NK[base]; v2 = edge[base];
    }
    lmn = fminf(lmn, fminf(v, v2)); lmx = fmaxf(lmx, fmaxf(v, v2));
  }
  blockMinMax(lmn, lmx, sred, slot4);
}

// ---------------- generic noise-split MFMA GEMM ----------------
// Z (+)= q*W + sum_i bit_i(2^i n_i). Block 64 rows x 128 cols; waves 2m x 2n (nfl col pairs).
// Per 32-byte K-chunk c: 8 noise kg (expand_mul x single-bf16 BN, depth-2 prefetch) + q-part (W hi/lo).
__global__ __launch_bounds__(256) void k_nsgemm(
    const unsigned char* __restrict__ Q, int ldq,
    const short* __restrict__ BNp, const short* __restrict__ BWp,
    int KCfull, int c0, int Nfull, int CB,
    float* __restrict__ Z, int accflag) {
  const int tid = threadIdx.x;
  const int lane = tid & 63, wave = tid >> 6;
  const int wm = wave >> 1, wn = wave & 1;
  const int l15 = lane & 15, l4 = lane >> 4;
  const int nfl[4] = {2 * wn, 2 * wn + 1, 2 * wn + 4, 2 * wn + 5};
  const int mbase = blockIdx.y * 64;
  const int nbase = blockIdx.x * 128;
  const int cstart = blockIdx.z * CB;
  size_t bbn[4], bbw[4];
  #pragma unroll
  for (int j = 0; j < 4; ++j) {
    size_t nf = (size_t)(nbase / 16 + nfl[j]);
    bbn[j] = nf * ((size_t)KCfull * 8) * 512 + (size_t)lane * 8;
    bbw[j] = nf * (size_t)KCfull * 2 * 512 + (size_t)lane * 8;
  }
  const unsigned char* qrow0 = Q + (size_t)(mbase + wm * 32 + l15) * ldq;
  const unsigned char* qrow1 = qrow0 + (size_t)16 * ldq;
  f4v acc[2][4];
  #pragma unroll
  for (int a = 0; a < 2; ++a)
    #pragma unroll
    for (int b = 0; b < 4; ++b) acc[a][b] = f4v{0.f, 0.f, 0.f, 0.f};
  const int kgs = (cstart + c0) * 8;
  s8v c0v[4], c1v[4];
  #pragma unroll
  for (int j = 0; j < 4; ++j) {
    c0v[j] = *(const s8v*)(BNp + bbn[j] + (size_t)kgs * 512);
    c1v[j] = *(const s8v*)(BNp + bbn[j] + (size_t)(kgs + 1) * 512);
  }
  for (int cl = 0; cl < CB; ++cl) {
    const int c = cstart + cl;       // local c (Q columns)
    const int cb = c + c0;           // B c
    s8v bwh[4];
    #pragma unroll
    for (int j = 0; j < 4; ++j)
      bwh[j] = *(const s8v*)(BWp + bbw[j] + (size_t)cb * 2 * 512);
    #pragma unroll
    for (int s = 0; s < 8; ++s) {
      const int kg = cb * 8 + s;
      unsigned w0 = *(const unsigned*)(qrow0 + c * 32 + s * 4);
      unsigned w1 = *(const unsigned*)(qrow1 + c * 32 + s * 4);
      s8v af0 = expand_mul((w0 >> (l4 * 8)) & 255u);
      s8v af1 = expand_mul((w1 >> (l4 * 8)) & 255u);
      s8v nx[4];
      #pragma unroll
      for (int j = 0; j < 4; ++j)   // depth-2 prefetch (tail over-reads stay inside workspace: harmless)
        nx[j] = *(const s8v*)(BNp + bbn[j] + (size_t)(kg + 2) * 512);
      #pragma unroll
      for (int j = 0; j < 4; ++j) {
        acc[0][j] = __builtin_amdgcn_mfma_f32_16x16x32_bf16(af0, c0v[j], acc[0][j], 0, 0, 0);
        acc[1][j] = __builtin_amdgcn_mfma_f32_16x16x32_bf16(af1, c0v[j], acc[1][j], 0, 0, 0);
      }
      #pragma unroll
      for (int j = 0; j < 4; ++j) { c0v[j] = c1v[j]; c1v[j] = nx[j]; }
    }
    // q-part: q bytes as bf16 x plain-W hi/lo
    {
      const int x = c * 32 + l4 * 8;
      unsigned a0 = *(const unsigned*)(qrow0 + x);
      unsigned a1 = *(const unsigned*)(qrow0 + x + 4);
      s8v aq0 = bytes_to_bf16(a0, a1);
      a0 = *(const unsigned*)(qrow1 + x);
      a1 = *(const unsigned*)(qrow1 + x + 4);
      s8v aq1 = bytes_to_bf16(a0, a1);
      #pragma unroll
      for (int j = 0; j < 4; ++j) {
        acc[0][j] = __builtin_amdgcn_mfma_f32_16x16x32_bf16(aq0, bwh[j], acc[0][j], 0, 0, 0);
        acc[1][j] = __builtin_amdgcn_mfma_f32_16x16x32_bf16(aq1, bwh[j], acc[1][j], 0, 0, 0);
        s8v bwl = *(const s8v*)(BWp + bbw[j] + ((size_t)cb * 2 + 1) * 512);
        acc[0][j] = __builtin_amdgcn_mfma_f32_16x16x32_bf16(aq0, bwl, acc[0][j], 0, 0, 0);
        acc[1][j] = __builtin_amdgcn_mfma_f32_16x16x32_bf16(aq1, bwl, acc[1][j], 0, 0, 0);
      }
    }
  }
  #pragma unroll
  for (int mf = 0; mf < 2; ++mf) {
    #pragma unroll
    for (int r = 0; r < 4; ++r) {
      int m = mbase + wm * 32 + mf * 16 + l4 * 4 + r;
      float* zp = Z + (size_t)m * Nfull + nbase;
      #pragma unroll
      for (int j = 0; j < 4; ++j) {
        int n = nfl[j] * 16 + l15;
        if (accflag == 0) zp[n] = acc[mf][j][r];
        else atomicAdd(zp + n, acc[mf][j][r]);
      }
    }
  }
}

// ---------------- K5: act1 minmax only (slot2) ----------------
__global__ __launch_bounds__(256) void k_act1(const float* __restrict__ z1, const float* __restrict__ rs,
                                              const unsigned* __restrict__ slot0,
                                              unsigned* __restrict__ slot1) {
  __shared__ float sred[512];
  const float mn = o2f(slot0[0]), mx = o2f(slot0[1]);
  int idx = blockIdx.x * 256 + threadIdx.x;
  float lmn = 3.4e38f, lmx = -3.4e38f;
  if (idx < R2 * 512) {
    int o = idx & 511;
    float v = fmaxf(0.f, z1[idx] * (1.f / 255.f) * (mx - mn) + mn * rs[o]);
    lmn = v; lmx = v;
  }
  blockMinMax(lmn, lmx, sred, slot1);
}

// ---------------- K6: quant2B (recompute act from z1) + quant3 ----------------
__global__ __launch_bounds__(256) void k_qq(
    const float* __restrict__ z1, const float* __restrict__ rs,
    const float* __restrict__ node, const float* __restrict__ edge,
    const float* __restrict__ c2in, const float* __restrict__ NK,
    const int* __restrict__ nidx, const unsigned* __restrict__ slot0,
    const unsigned* __restrict__ slot2, const unsigned* __restrict__ slot4,
    unsigned char* __restrict__ Q2B, unsigned char* __restrict__ QP2, unsigned char* __restrict__ QP3) {
  int idx = blockIdx.x * 256 + threadIdx.x;
  if (idx < R2 * 512) {
    const float mn0 = o2f(slot0[0]), mx0 = o2f(slot0[1]);
    const float mn = o2f(slot2[0]), mx = o2f(slot2[1]);
    int o = idx & 511;
    float v = fmaxf(0.f, z1[idx] * (1.f / 255.f) * (mx0 - mn0) + mn0 * rs[o]);
    Q2B[idx] = (unsigned char)((v - mn) * (255.f / (mx - mn)));
    return;
  }
  int j = idx - R2 * 512;
  const int seg = 245760;
  if (j >= 5 * seg) return;
  const float mn = o2f(slot4[0]), mx = o2f(slot4[1]);
  const float invd = 255.f / (mx - mn);
  int s = j / seg; int jj = j - s * seg;
  int r = jj >> 6, c = jj & 63;
  float v; unsigned char* dst;
  if (s == 0)      { v = node[(size_t)(r / 20) * 64 + c];  dst = QP2 + (size_t)r * 192 + c; }
  else if (s == 1) { v = c2in[(size_t)r * 128 + 64 + c];   dst = QP2 + (size_t)r * 192 + 64 + c; }
  else if (s == 2) { v = edge[(size_t)r * 64 + c];         dst = QP2 + (size_t)r * 192 + 128 + c; }
  else if (s == 3) { v = NK[(size_t)r * 64 + c];           dst = QP3 + (size_t)r * 128 + c; }
  else             { v = edge[(size_t)r * 64 + c];         dst = QP3 + (size_t)r * 128 + 64 + c; }
  *dst = (unsigned char)((v - mn) * invd);
}

// ---------------- K9: act2 + minmax3 (slot6) ----------------
__global__ __launch_bounds__(256) void k_act2mm3(
    const float* __restrict__ z2, const float* __restrict__ rs2b,
    const unsigned* __restrict__ slot2, float* __restrict__ two,
    const float* __restrict__ P12, const float* __restrict__ P3,
    const float* __restrict__ rs3a, const int* __restrict__ nidx,
    const unsigned* __restrict__ slot4, unsigned* __restrict__ slot6) {
  __shared__ float p12s[640];
  __shared__ float bias[640];
  __shared__ float sred[512];
  int gid = blockIdx.x * 256 + threadIdx.x;
  if (gid < R2 * 64) {
    const float mn = o2f(slot2[0]), mx = o2f(slot2[1]);
    int row = gid >> 6, c = gid & 63;
    float d = (mx - mn) * (1.f / 255.f);
    float g = z2[(size_t)row * 128 + c] * d + mn * rs2b[c];
    float e = z2[(size_t)row * 128 + 64 + c] * d + mn * rs2b[64 + c];
    two[gid] = (1.f / (1.f + expf(-g))) * tanhf(e);
  }
  const int bij = blockIdx.x;
  const int b = bij / 960;
  const int jp = nidx[bij];
  const size_t p3b = (size_t)((b * 48 + jp) * 20) * 640;
  const float mn2 = o2f(slot4[0]), mx2 = o2f(slot4[1]);
  const float sc2 = (mx2 - mn2) * (1.f / 255.f);
  for (int k = threadIdx.x; k < 640; k += 256) {
    p12s[k] = P12[(size_t)bij * 640 + k];
    bias[k] = mn2 * rs3a[k];
  }
  __syncthreads();
  float lmn = 3.4e38f, lmx = -3.4e38f;
  for (int t = threadIdx.x; t < 20 * 640; t += 256) {
    int knb = t / 640, k = t - knb * 640;
    float v = fmaxf(0.f, (p12s[k] + P3[p3b + t]) * sc2 + bias[k]);
    lmn = fminf(lmn, v); lmx = fmaxf(lmx, v);
  }
  blockMinMax(lmn, lmx, sred, slot6);
}

// ---------------- K10: fused 3-body layer 2 (round-6 schedule, no setprio) ----------------
__global__ __launch_bounds__(256) void k_mfma_l3b(
    const float* __restrict__ P12, const float* __restrict__ P3,
    const float* __restrict__ rs3a, const float* __restrict__ rs3b,
    const short* __restrict__ BW, const short* __restrict__ BN,
    const int* __restrict__ nidx, const float* __restrict__ mask,
    const unsigned* __restrict__ slotA, const unsigned* __restrict__ slotB,
    float* __restrict__ tsum) {
  __shared__ unsigned char qt[64 * 648];   // 648-byte pad: conflict-free
  const int tid = threadIdx.x;
  const int s0 = blockIdx.x * 64;
  const float mn2 = o2f(slotA[0]), mx2 = o2f(slotA[1]);
  const float mn3 = o2f(slotB[0]), mx3 = o2f(slotB[1]);
  const float sc2 = (mx2 - mn2) * (1.f / 255.f);
  const float invd3 = 255.f / (mx3 - mn3);
  {
    int r = tid >> 2, kq = (tid & 3) * 160;
    int s = s0 + r;
    int bij = s / 20, knb = s - bij * 20, b = bij / 960;
    int p3row = (b * 48 + nidx[bij]) * 20 + knb;
    const float* pa = P12 + (size_t)bij * 640;
    const float* pb = P3 + (size_t)p3row * 640;
    for (int k = kq; k < kq + 160; k += 4) {
      float4 va = *(const float4*)(pa + k);
      float4 vb = *(const float4*)(pb + k);
      float4 rv = *(const float4*)(rs3a + k);
      float v0 = fmaxf(0.f, (va.x + vb.x) * sc2 + mn2 * rv.x);
      float v1 = fmaxf(0.f, (va.y + vb.y) * sc2 + mn2 * rv.y);
      float v2 = fmaxf(0.f, (va.z + vb.z) * sc2 + mn2 * rv.z);
      float v3 = fmaxf(0.f, (va.w + vb.w) * sc2 + mn2 * rv.w);
      unsigned pk = (unsigned)((v0 - mn3) * invd3) | ((unsigned)((v1 - mn3) * invd3) << 8)
                  | ((unsigned)((v2 - mn3) * invd3) << 16) | ((unsigned)((v3 - mn3) * invd3) << 24);
      *(unsigned*)(&qt[(size_t)r * 648 + k]) = pk;
    }
  }
  __syncthreads();
  const int lane = tid & 63, wave = tid >> 6;
  const int wm = wave >> 1, wn = wave & 1;
  const int l15 = lane & 15, l4 = lane >> 4;
  const int nfl[4] = {2 * wn, 2 * wn + 1, 2 * wn + 4, 2 * wn + 5};
  size_t bb[4];
  #pragma unroll
  for (int j = 0; j < 4; ++j) bb[j] = ((size_t)nfl[j] * 160) * 512 + (size_t)lane * 8;
  f4v acc[2][4];
  #pragma unroll
  for (int a = 0; a < 2; ++a)
    #pragma unroll
    for (int b = 0; b < 4; ++b) acc[a][b] = f4v{0.f, 0.f, 0.f, 0.f};
  s8v c0[4], c1[4];
  #pragma unroll
  for (int j = 0; j < 4; ++j) {
    c0[j] = *(const s8v*)(BN + bb[j]);
    c1[j] = *(const s8v*)(BN + bb[j] + 512);
  }
  const unsigned char* qrow0 = &qt[(size_t)(wm * 32 + l15) * 648];
  const unsigned char* qrow1 = qrow0 + 16 * 648;
  for (int c = 0; c < 20; ++c) {
    s8v bwh[4];
    #pragma unroll
    for (int j = 0; j < 4; ++j)
      bwh[j] = *(const s8v*)(BW + (((size_t)nfl[j] * 20 + c) * 2) * 512 + (size_t)lane * 8);
    #pragma unroll
    for (int s = 0; s < 8; ++s) {
      const int kg = c * 8 + s;
      unsigned w0 = *(const unsigned*)(qrow0 + kg * 4);
      unsigned w1 = *(const unsigned*)(qrow1 + kg * 4);
      s8v af0 = expand_mul((w0 >> (l4 * 8)) & 255u);
      s8v af1 = expand_mul((w1 >> (l4 * 8)) & 255u);
      s8v nx[4];
      #pragma unroll
      for (int j = 0; j < 4; ++j)
        nx[j] = *(const s8v*)(BN + bb[j] + (size_t)(kg + 2) * 512);
      #pragma unroll
      for (int j = 0; j < 4; ++j) {
        acc[0][j] = __builtin_amdgcn_mfma_f32_16x16x32_bf16(af0, c0[j], acc[0][j], 0, 0, 0);
        acc[1][j] = __builtin_amdgcn_mfma_f32_16x16x32_bf16(af1, c0[j], acc[1][j], 0, 0, 0);
      }
      #pragma unroll
      for (int j = 0; j < 4; ++j) { c0[j] = c1[j]; c1[j] = nx[j]; }
    }
    {
      const int x = c * 32 + l4 * 8;
      unsigned a0 = *(const unsigned*)(qrow0 + x);
      unsigned a1 = *(const unsigned*)(qrow0 + x + 4);
      s8v aq0 = bytes_to_bf16(a0, a1);
      a0 = *(const unsigned*)(qrow1 + x);
      a1 = *(const unsigned*)(qrow1 + x + 4);
      s8v aq1 = bytes_to_bf16(a0, a1);
      #pragma unroll
      for (int j = 0; j < 4; ++j) {
        acc[0][j] = __builtin_amdgcn_mfma_f32_16x16x32_bf16(aq0, bwh[j], acc[0][j], 0, 0, 0);
        acc[1][j] = __builtin_amdgcn_mfma_f32_16x16x32_bf16(aq1, bwh[j], acc[1][j], 0, 0, 0);
        s8v bwl = *(const s8v*)(BW + ((((size_t)nfl[j] * 20 + c) * 2) + 1) * 512 + (size_t)lane * 8);
        acc[0][j] = __builtin_amdgcn_mfma_f32_16x16x32_bf16(aq0, bwl, acc[0][j], 0, 0, 0);
        acc[1][j] = __builtin_amdgcn_mfma_f32_16x16x32_bf16(aq1, bwl, acc[1][j], 0, 0, 0);
      }
    }
  }
  const float d3 = (mx3 - mn3) * (1.f / 255.f);
  float rg[2], re[2];
  #pragma unroll
  for (int j = 0; j < 2; ++j) {
    int gcol = (2 * wn + j) * 16 + l15;
    rg[j] = mn3 * rs3b[gcol];
    re[j] = mn3 * rs3b[64 + gcol];
  }
  #pragma unroll
  for (int mf = 0; mf < 2; ++mf) {
    #pragma unroll
    for (int r = 0; r < 4; ++r) {
      int s = s0 + wm * 32 + mf * 16 + l4 * 4 + r;
      int bij = s / 20, knb = s - bij * 20, b = bij / 960;
      int p3row = (b * 48 + nidx[bij]) * 20 + knb;
      float mk = mask[p3row];
      #pragma unroll
      for (int j = 0; j < 2; ++j) {
        float g = acc[mf][j][r] * d3 + rg[j];
        float e = acc[mf][j + 2][r] * d3 + re[j];
        float val = (1.f / (1.f + expf(-g))) * tanhf(e) * mk;
        atomicAdd(&tsum[(size_t)bij * 64 + (2 * wn + j) * 16 + l15], val);
      }
    }
  }
}

// ---------------- K11/K12: BN stats + final ----------------
__global__ __launch_bounds__(256) void k_bnstats2(const float* __restrict__ two, const float* __restrict__ tsum,
                                                  float* __restrict__ bn) {
  __shared__ float ss[512];
  const float* x = blockIdx.y ? tsum : two;
  float* mout = bn + (blockIdx.y ? 128 : 0);
  float* vout = mout + 64;
  int c = blockIdx.x, t = threadIdx.x;
  float s = 0.f, q = 0.f;
  for (int r = t; r < R2; r += 256) { float v = x[(size_t)r * 64 + c]; s += v; q += v * v; }
  ss[t] = s; ss[256 + t] = q;
  __syncthreads();
  for (int st = 128; st > 0; st >>= 1) {
    if (t < st) { ss[t] += ss[t + st]; ss[256 + t] += ss[256 + t + st]; }
    __syncthreads();
  }
  if (t == 0) { float m = ss[0] / (float)R2; mout[c] = m; vout[c] = ss[256] / (float)R2 - m * m; }
}

__global__ __launch_bounds__(256) void k_final(const float* __restrict__ edge, const float* __restrict__ two,
                                               const float* __restrict__ tsum, const float* __restrict__ bn,
                                               const float* __restrict__ g2, const float* __restrict__ b2,
                                               const float* __restrict__ g3, const float* __restrict__ b3,
                                               float* __restrict__ out) {
  int idx = blockIdx.x * 256 + threadIdx.x;
  if (idx >= R2 * 64) return;
  int c = idx & 63;
  float t2 = (two[idx] - bn[c]) / sqrtf(bn[64 + c] + 1e-5f) * g2[c] + b2[c];
  float t3 = (tsum[idx] - bn[128 + c]) / sqrtf(bn[192 + c] + 1e-5f) * g3[c] + b3[c];
  out[idx] = fmaxf(0.f, edge[idx] + t2 + t3);
}

// ---------------- host launcher ----------------
extern "C" void kernel_launch(void* const* d_in, const int* in_sizes, int n_in,
                              void* d_out, int out_size, void* d_ws, size_t ws_size,
                              hipStream_t stream) {
  (void)in_sizes; (void)n_in; (void)out_size; (void)ws_size;
  const float* node   = (const float*)d_in[0];
  const float* edge   = (const float*)d_in[1];
  const float* mask   = (const float*)d_in[2];
  const float* c_two  = (const float*)d_in[3];
  const float* c_two2 = (const float*)d_in[4];
  const float* c_three  = (const float*)d_in[5];
  const float* c_three2 = (const float*)d_in[6];
  const float* bn2g = (const float*)d_in[7];
  const float* bn2b = (const float*)d_in[8];
  const float* bn3g = (const float*)d_in[9];
  const float* bn3b = (const float*)d_in[10];
  const int*   nidx = (const int*)d_in[11];
  float* ws = (float*)d_ws;
  unsigned* slots = (unsigned*)(ws + OFF_SLOT);
  float* out = (float*)d_out;
  short* BN2A = (short*)(ws + OFF_BN2A); short* BW2A = (short*)(ws + OFF_BW2A);
  short* BN2B = (short*)(ws + OFF_BN2B); short* BW2B = (short*)(ws + OFF_BW2B);
  short* BN3A = (short*)(ws + OFF_BN3A); short* BW3A = (short*)(ws + OFF_BW3A);
  short* BN3B = (short*)(ws + OFF_BN3B); short* BW3B = (short*)(ws + OFF_BW3B);
  unsigned char* Q2A = (unsigned char*)(ws + OFF_Q2A);
  unsigned char* Q2B = (unsigned char*)(ws + OFF_Q2B);
  unsigned char* QP2 = (unsigned char*)(ws + OFF_QP2);
  unsigned char* QP3 = (unsigned char*)(ws + OFF_QP3);
  float* RS = ws + OFF_RS;

  // K1: init + expanded weights (uniform noise-split)
  k_prep<<<7680, 256, 0, stream>>>(c_two, c_two2, c_three, c_three2,
                                   BN2A, BW2A, BN2B, BW2B, BN3A, BW3A, BN3B, BW3B,
                                   ws + OFF_W72A, ws + OFF_W72B, ws + OFF_W73A, ws + OFF_W73B,
                                   ws + OFF_Z1, ws + OFF_Z2, ws + OFF_TSUM, slots);
  // K2: build c2in/NK + rowsums + slot0
  k_build2<<<2886, 256, 0, stream>>>(node, mask, nidx, ws + OFF_C2IN, ws + OFF_NK,
                                     ws + OFF_W72A, ws + OFF_W72B, ws + OFF_W73A, ws + OFF_W73B,
                                     RS, slots + 0);
  // K3: quant2A + 3-body minmax (slot4)
  k_qm4<<<2048, 256, 0, stream>>>(node, edge, ws + OFF_C2IN, ws + OFF_NK, nidx, slots + 0,
                                  Q2A, slots + 4);
  // K4: 2-body layer 1 (noise-split, K=128 -> 4 c-chunks, z=2)
  k_nsgemm<<<dim3(4, 60, 2), 256, 0, stream>>>(Q2A, 128, BN2A, BW2A, 4, 0, 512, 2, ws + OFF_Z1, 3);
  // K5: act1 minmax (slot2)
  k_act1<<<7680, 256, 0, stream>>>(ws + OFF_Z1, RS, slots + 0, slots + 2);
  // K6: quant2B (from z1) + quant3
  k_qq<<<12480, 256, 0, stream>>>(ws + OFF_Z1, RS, node, edge, ws + OFF_C2IN, ws + OFF_NK,
                                  nidx, slots + 0, slots + 2, slots + 4, Q2B, QP2, QP3);
  // K7: 2-body layer 2 (K=512 -> 16 c-chunks, z=4)
  k_nsgemm<<<dim3(1, 60, 4), 256, 0, stream>>>(Q2B, 512, BN2B, BW2B, 16, 0, 128, 4, ws + OFF_Z2, 3);
  // K8a: P2 (K=192 -> 6 c-chunks at B offset 0)
  k_nsgemm<<<dim3(5, 60, 1), 256, 0, stream>>>(QP2, 192, BN3A, BW3A, 10, 0, 640, 6, ws + OFF_P2, 0);
  // K8b: P3 (K=128 -> 4 c-chunks at B offset 6 = byte col 192)
  k_nsgemm<<<dim3(5, 60, 1), 256, 0, stream>>>(QP3, 128, BN3A, BW3A, 10, 6, 640, 4, ws + OFF_P3, 0);
  // K9: act2 + minmax3 (slot6)
  k_act2mm3<<<3840, 256, 0, stream>>>(ws + OFF_Z2, RS + 512, slots + 2, ws + OFF_TWO,
                                      ws + OFF_P2, ws + OFF_P3, RS + 640, nidx, slots + 4, slots + 6);
  // K10: fused 3-body layer 2 (round-6 schedule)
  k_mfma_l3b<<<1200, 256, 0, stream>>>(ws + OFF_P2, ws + OFF_P3, RS + 640, RS + 1280,
                                       BW3B, BN3B, nidx, mask, slots + 4, slots + 6, ws + OFF_TSUM);
  // K11/K12
  k_bnstats2<<<dim3(64, 2), 256, 0, stream>>>(ws + OFF_TWO, ws + OFF_TSUM, ws + OFF_BN);
  k_final<<<960, 256, 0, stream>>>(edge, ws + OFF_TWO, ws + OFF_TSUM, ws + OFF_BN,
                                   bn2g, bn2b, bn3g, bn3b, out);
}

// Round 12
// 772.704 us; speedup vs baseline: 1.1850x; 1.0337x over previous
//
#include <hip/hip_runtime.h>
#include <cstdint>
#include <cstddef>

#define DEVI __device__ __forceinline__

typedef __attribute__((ext_vector_type(8))) short s8v;   // 8 bf16 bit patterns
typedef __attribute__((ext_vector_type(4))) float f4v;

static constexpr int B_ = 4, AT = 48, NBRS = 20;
static constexpr int R2 = B_ * AT * NBRS;   // 3840 (b,i,j) rows
static constexpr int M4 = R2 * NBRS;        // 76800 (b,i,j,k) rows

// ---------------- workspace layout (float offsets) ----------------
static constexpr size_t OFF_BN2A = 0;                          // 512x128:  262144
static constexpr size_t OFF_BW2A = OFF_BN2A + 262144;          // 65536
static constexpr size_t OFF_BN2B = OFF_BW2A + 65536;           // 128x512:  262144
static constexpr size_t OFF_BW2B = OFF_BN2B + 262144;          // 65536
static constexpr size_t OFF_BN3A = OFF_BW2B + 65536;           // 640x320:  819200 (col-permuted)
static constexpr size_t OFF_BW3A = OFF_BN3A + 819200;          // 204800
static constexpr size_t OFF_BN3B = OFF_BW3A + 204800;          // 128x640:  327680
static constexpr size_t OFF_BW3B = OFF_BN3B + 327680;          // 81920
static constexpr size_t OFF_W72A = OFF_BW3B + 81920;           // 512x128 f (bit-7 noisy)
static constexpr size_t OFF_W72B = OFF_W72A + 65536;           // 128x512 f
static constexpr size_t OFF_W73A = OFF_W72B + 65536;           // 640x320 f
static constexpr size_t OFF_W73B = OFF_W73A + 204800;          // 128x640 f
static constexpr size_t OFF_RS   = OFF_W73B + 81920;           // 1408
static constexpr size_t OFF_SLOT = OFF_RS + 1408;              // 16
static constexpr size_t OFF_BN   = OFF_SLOT + 16;              // 256
static constexpr size_t OFF_C2IN = OFF_BN + 256;               // 3840x128
static constexpr size_t OFF_Z1   = OFF_C2IN + (size_t)R2 * 128;
static constexpr size_t OFF_Z2   = OFF_Z1 + (size_t)R2 * 512;
static constexpr size_t OFF_TWO  = OFF_Z2 + (size_t)R2 * 128;
static constexpr size_t OFF_NK   = OFF_TWO + (size_t)R2 * 64;
static constexpr size_t OFF_P2   = OFF_NK + (size_t)R2 * 64;   // 3840x640
static constexpr size_t OFF_P3   = OFF_P2 + (size_t)R2 * 640;
static constexpr size_t OFF_TSUM = OFF_P3 + (size_t)R2 * 640;
static constexpr size_t OFF_Q2A  = OFF_TSUM + (size_t)R2 * 64; // 3840x128 bytes
static constexpr size_t OFF_Q2B  = OFF_Q2A + 122880;           // 3840x512 bytes
static constexpr size_t OFF_QP2  = OFF_Q2B + 491520;           // 3840x192 bytes
static constexpr size_t OFF_QP3  = OFF_QP2 + 184320;           // 3840x128 bytes

// ---------------- threefry-2x32 (JAX-compatible, verified) ----------------
DEVI void tf2x32(unsigned k0, unsigned k1, unsigned x0, unsigned x1,
                 unsigned& o0, unsigned& o1) {
  unsigned ks0 = k0, ks1 = k1, ks2 = k0 ^ k1 ^ 0x1BD11BDAu;
  x0 += ks0; x1 += ks1;
  const unsigned rotA[4] = {13u, 15u, 26u, 6u};
  const unsigned rotB[4] = {17u, 29u, 16u, 24u};
  unsigned ks[3] = {ks0, ks1, ks2};
  #pragma unroll
  for (int i = 0; i < 5; ++i) {
    const unsigned* rot = (i & 1) ? rotB : rotA;
    #pragma unroll
    for (int r = 0; r < 4; ++r) {
      x0 += x1;
      x1 = (x1 << rot[r]) | (x1 >> (32u - rot[r]));
      x1 ^= x0;
    }
    x0 += ks[(i + 1) % 3];
    x1 += ks[(i + 2) % 3] + (unsigned)(i + 1);
  }
  o0 = x0; o1 = x1;
}

DEVI float erfinv_xla(float x) {
  float w = -log1pf(-x * x);
  float p;
  if (w < 5.f) {
    w -= 2.5f;
    p = 2.81022636e-08f;
    p = fmaf(p, w, 3.43273939e-07f);
    p = fmaf(p, w, -3.5233877e-06f);
    p = fmaf(p, w, -4.39150654e-06f);
    p = fmaf(p, w, 0.00021858087f);
    p = fmaf(p, w, -0.00125372503f);
    p = fmaf(p, w, -0.00417768164f);
    p = fmaf(p, w, 0.246640727f);
    p = fmaf(p, w, 1.50140941f);
  } else {
    w = sqrtf(w) - 3.f;
    p = -0.000200214257f;
    p = fmaf(p, w, 0.000100950558f);
    p = fmaf(p, w, 0.00134934322f);
    p = fmaf(p, w, -0.00367342844f);
    p = fmaf(p, w, 0.00573950773f);
    p = fmaf(p, w, -0.0076224613f);
    p = fmaf(p, w, 0.00943887047f);
    p = fmaf(p, w, 1.00167406f);
    p = fmaf(p, w, 2.83297682f);
  }
  return p * x;
}

DEVI float normal_from_bits(unsigned bits) {
  unsigned fb = (bits >> 9) | 0x3F800000u;
  float f = __uint_as_float(fb) - 1.0f;
  const float lo = -0.99999994f;
  float u = f * (1.0f - lo) + lo;
  u = fmaxf(lo, u);
  return 1.41421356237f * erfinv_xla(u);
}

DEVI unsigned f2o(float f) { unsigned u = __float_as_uint(f); return (u & 0x80000000u) ? ~u : (u | 0x80000000u); }
DEVI float o2f(unsigned u) { return (u & 0x80000000u) ? __uint_as_float(u & 0x7FFFFFFFu) : __uint_as_float(~u); }

DEVI unsigned short f2bf(float x) {  // RNE f32 -> bf16
  unsigned u = __float_as_uint(x);
  return (unsigned short)((u + 0x7FFFu + ((u >> 16) & 1u)) >> 16);
}
DEVI float bf2f(unsigned short h) { return __uint_as_float((unsigned)h << 16); }

DEVI void blockMinMax(float lmn, float lmx, float* smem, unsigned* slot) {
  float* smn = smem; float* smx = smem + 256;
  int t = threadIdx.x;
  smn[t] = lmn; smx[t] = lmx;
  __syncthreads();
  for (int s = 128; s > 0; s >>= 1) {
    if (t < s) { smn[t] = fminf(smn[t], smn[t + s]); smx[t] = fmaxf(smx[t], smx[t + s]); }
    __syncthreads();
  }
  if (t == 0) { atomicMin(slot + 0, f2o(smn[0])); atomicMax(slot + 1, f2o(smx[0])); }
}

// bit-spread expansion: byte b -> 8 bf16 {0,1} in PERMUTED elem order {0,2,1,3,4,6,5,7}
DEVI s8v expand_mul(unsigned b) {
  unsigned sl = (b & 15u) * 0x00204081u;
  unsigned sh = ((b >> 4) & 15u) * 0x00204081u;
  union { unsigned u[4]; s8v s; } r;
  r.u[0] = (sl & 0x00010001u) * 0x3F80u;
  r.u[1] = ((sl >> 8) & 0x00010001u) * 0x3F80u;
  r.u[2] = (sh & 0x00010001u) * 0x3F80u;
  r.u[3] = ((sh >> 8) & 0x00010001u) * 0x3F80u;
  return r.s;
}
// matching store-side permutation (involution: 1<->2, 5<->6)
DEVI constexpr int bperm(int bit) { return bit ^ ((((bit) ^ (bit >> 1)) & 1) * 3); }

// 8 q-bytes (two u32) -> 8 bf16 (exact for 0..255), natural order
DEVI s8v bytes_to_bf16(unsigned a, unsigned b) {
  union { unsigned u[4]; s8v s; } r;
  float f0 = (float)(a & 255u), f1 = (float)((a >> 8) & 255u);
  float f2 = (float)((a >> 16) & 255u), f3 = (float)(a >> 24);
  r.u[0] = (__float_as_uint(f0) >> 16) | (__float_as_uint(f1) & 0xFFFF0000u);
  r.u[1] = (__float_as_uint(f2) >> 16) | (__float_as_uint(f3) & 0xFFFF0000u);
  f0 = (float)(b & 255u); f1 = (float)((b >> 8) & 255u);
  f2 = (float)((b >> 16) & 255u); f3 = (float)(b >> 24);
  r.u[2] = (__float_as_uint(f0) >> 16) | (__float_as_uint(f1) & 0xFFFF0000u);
  r.u[3] = (__float_as_uint(f2) >> 16) | (__float_as_uint(f3) & 0xFFFF0000u);
  return r.s;
}

// shared noise-split GEMM body: Z-tile (+)= q*W + sum_i bit_i(2^i n_i)
DEVI void nsgemm_body(const unsigned char* __restrict__ Q, int ldq,
                      const short* __restrict__ BNp, const short* __restrict__ BWp,
                      int KCfull, int c0, int Nfull, int CB, int cstart,
                      int mbase, int nbase, float* __restrict__ Z, int accflag) {
  const int tid = threadIdx.x;
  const int lane = tid & 63, wave = tid >> 6;
  const int wm = wave >> 1, wn = wave & 1;
  const int l15 = lane & 15, l4 = lane >> 4;
  const int nfl[4] = {2 * wn, 2 * wn + 1, 2 * wn + 4, 2 * wn + 5};
  size_t bbn[4], bbw[4];
  #pragma unroll
  for (int j = 0; j < 4; ++j) {
    size_t nf = (size_t)(nbase / 16 + nfl[j]);
    bbn[j] = nf * ((size_t)KCfull * 8) * 512 + (size_t)lane * 8;
    bbw[j] = nf * (size_t)KCfull * 2 * 512 + (size_t)lane * 8;
  }
  const unsigned char* qrow0 = Q + (size_t)(mbase + wm * 32 + l15) * ldq;
  const unsigned char* qrow1 = qrow0 + (size_t)16 * ldq;
  f4v acc[2][4];
  #pragma unroll
  for (int a = 0; a < 2; ++a)
    #pragma unroll
    for (int b = 0; b < 4; ++b) acc[a][b] = f4v{0.f, 0.f, 0.f, 0.f};
  const int kgs = (cstart + c0) * 8;
  s8v c0v[4], c1v[4];
  #pragma unroll
  for (int j = 0; j < 4; ++j) {
    c0v[j] = *(const s8v*)(BNp + bbn[j] + (size_t)kgs * 512);
    c1v[j] = *(const s8v*)(BNp + bbn[j] + (size_t)(kgs + 1) * 512);
  }
  for (int cl = 0; cl < CB; ++cl) {
    const int c = cstart + cl;
    const int cb = c + c0;
    s8v bwh[4];
    #pragma unroll
    for (int j = 0; j < 4; ++j)
      bwh[j] = *(const s8v*)(BWp + bbw[j] + (size_t)cb * 2 * 512);
    #pragma unroll
    for (int s = 0; s < 8; ++s) {
      const int kg = cb * 8 + s;
      unsigned w0 = *(const unsigned*)(qrow0 + c * 32 + s * 4);
      unsigned w1 = *(const unsigned*)(qrow1 + c * 32 + s * 4);
      s8v af0 = expand_mul((w0 >> (l4 * 8)) & 255u);
      s8v af1 = expand_mul((w1 >> (l4 * 8)) & 255u);
      s8v nx[4];
      #pragma unroll
      for (int j = 0; j < 4; ++j)   // depth-2 prefetch (tail over-reads stay inside workspace: harmless)
        nx[j] = *(const s8v*)(BNp + bbn[j] + (size_t)(kg + 2) * 512);
      #pragma unroll
      for (int j = 0; j < 4; ++j) {
        acc[0][j] = __builtin_amdgcn_mfma_f32_16x16x32_bf16(af0, c0v[j], acc[0][j], 0, 0, 0);
        acc[1][j] = __builtin_amdgcn_mfma_f32_16x16x32_bf16(af1, c0v[j], acc[1][j], 0, 0, 0);
      }
      #pragma unroll
      for (int j = 0; j < 4; ++j) { c0v[j] = c1v[j]; c1v[j] = nx[j]; }
    }
    {
      const int x = c * 32 + l4 * 8;
      unsigned a0 = *(const unsigned*)(qrow0 + x);
      unsigned a1 = *(const unsigned*)(qrow0 + x + 4);
      s8v aq0 = bytes_to_bf16(a0, a1);
      a0 = *(const unsigned*)(qrow1 + x);
      a1 = *(const unsigned*)(qrow1 + x + 4);
      s8v aq1 = bytes_to_bf16(a0, a1);
      #pragma unroll
      for (int j = 0; j < 4; ++j) {
        acc[0][j] = __builtin_amdgcn_mfma_f32_16x16x32_bf16(aq0, bwh[j], acc[0][j], 0, 0, 0);
        acc[1][j] = __builtin_amdgcn_mfma_f32_16x16x32_bf16(aq1, bwh[j], acc[1][j], 0, 0, 0);
        s8v bwl = *(const s8v*)(BWp + bbw[j] + ((size_t)cb * 2 + 1) * 512);
        acc[0][j] = __builtin_amdgcn_mfma_f32_16x16x32_bf16(aq0, bwl, acc[0][j], 0, 0, 0);
        acc[1][j] = __builtin_amdgcn_mfma_f32_16x16x32_bf16(aq1, bwl, acc[1][j], 0, 0, 0);
      }
    }
  }
  #pragma unroll
  for (int mf = 0; mf < 2; ++mf) {
    #pragma unroll
    for (int r = 0; r < 4; ++r) {
      int m = mbase + wm * 32 + mf * 16 + l4 * 4 + r;
      float* zp = Z + (size_t)m * Nfull + nbase;
      #pragma unroll
      for (int j = 0; j < 4; ++j) {
        int n = nfl[j] * 16 + l15;
        if (accflag == 0) zp[n] = acc[mf][j][r];
        else atomicAdd(zp + n, acc[mf][j][r]);
      }
    }
  }
}

// ---------------- K1: init + all expanded weights (uniform noise-split) ----------------
__global__ __launch_bounds__(256) void k_prep(
    const float* __restrict__ W2A, const float* __restrict__ W2B,
    const float* __restrict__ W3A, const float* __restrict__ W3B,
    short* __restrict__ BN2A, short* __restrict__ BW2A,
    short* __restrict__ BN2B, short* __restrict__ BW2B,
    short* __restrict__ BN3A, short* __restrict__ BW3A,
    short* __restrict__ BN3B, short* __restrict__ BW3B,
    float* __restrict__ W72A, float* __restrict__ W72B,
    float* __restrict__ W73A, float* __restrict__ W73B,
    float* __restrict__ z1, float* __restrict__ z2, float* __restrict__ tsum,
    unsigned* __restrict__ slots) {
  int t = blockIdx.x * 256 + threadIdx.x;
  if (t < R2 * 512) z1[t] = 0.f;
  if (t < R2 * 128) z2[t] = 0.f;
  if (t < R2 * 64) tsum[t] = 0.f;
  if (t < 4) { slots[2 * t] = f2o(3.402823466e38f); slots[2 * t + 1] = f2o(-3.402823466e38f); }
  int lt = t;
  const float* W; float* W7; short* BNp; short* BWp; int K; unsigned layer; int which;
  if (lt < 65536) { W = W2A; W7 = W72A; BNp = BN2A; BWp = BW2A; K = 128; layer = 0u; which = 0; }
  else if ((lt -= 65536) < 65536) { W = W2B; W7 = W72B; BNp = BN2B; BWp = BW2B; K = 512; layer = 1u; which = 1; }
  else if ((lt -= 65536) < 204800) { W = W3A; W7 = W73A; BNp = BN3A; BWp = BW3A; K = 320; layer = 2u; which = 2; }
  else if ((lt -= 204800) < 81920) { W = W3B; W7 = W73B; BNp = BN3B; BWp = BW3B; K = 640; layer = 3u; which = 3; }
  else return;
  int e = lt;
  int n = e / K, k = e - n * K;
  float w = W[e];
  float aw = fabsf(w) * 0.1f;
  unsigned kl0, kl1;
  tf2x32(0u, 42u, 0u, layer, kl0, kl1);
  union { short s[8]; s8v v; } bnv;
  #pragma unroll
  for (int bit = 0; bit < 8; ++bit) {
    unsigned kb0, kb1, r0, r1;
    tf2x32(kl0, kl1, 0u, (unsigned)bit, kb0, kb1);
    tf2x32(kb0, kb1, 0u, (unsigned)e, r0, r1);
    float nz = normal_from_bits(r0 ^ r1) * aw;
    if (bit == 7) W7[e] = w + nz;
    bnv.s[bperm(bit)] = (short)f2bf(ldexpf(nz, bit));
  }
  int pk = k;
  if (which == 2) {
    if (k >= 128 && k < 192) pk = k + 64;        // node_k -> 192..256
    else if (k >= 192 && k < 256) pk = k - 64;   // edge_ij -> 128..192
  }
  *(s8v*)(BNp + ((size_t)(n >> 4) * (K >> 2) + (size_t)(pk >> 2)) * 512
              + (size_t)((pk & 3) * 16 + (n & 15)) * 8) = bnv.v;
  unsigned short hi = f2bf(w);
  unsigned short lo = f2bf(w - bf2f(hi));
  size_t o2 = (((size_t)(n >> 4) * (K >> 5) + (size_t)(pk >> 5)) * 2) * 512
            + (size_t)(((pk >> 3) & 3) * 16 + (n & 15)) * 8 + (pk & 7);
  BWp[o2] = (short)hi; BWp[o2 + 512] = (short)lo;
}

// ---------------- K2: c2in build + NK gather + rowsums (+slot0 minmax) ----------------
__global__ __launch_bounds__(256) void k_build2(
    const float* __restrict__ node, const float* __restrict__ mask,
    const int* __restrict__ nidx, float* __restrict__ c2in, float* __restrict__ NK,
    const float* __restrict__ W72A, const float* __restrict__ W72B,
    const float* __restrict__ W73A, const float* __restrict__ W73B,
    float* __restrict__ rs, unsigned* __restrict__ slot) {
  __shared__ float sred[512];
  int idx = blockIdx.x * 256 + threadIdx.x;
  float lmn = 3.4e38f, lmx = -3.4e38f;
  if (idx < R2 * 128) {
    int row = idx >> 7, c = idx & 127;
    float v;
    if (c < 64) v = node[(size_t)(row / 20) * 64 + c];
    else {
      int b = row / 960;
      v = node[(size_t)(b * 48 + nidx[row]) * 64 + (c - 64)] * mask[row];
    }
    c2in[idx] = v; lmn = v; lmx = v;
  } else if (idx < R2 * 192) {
    int i2 = idx - R2 * 128;
    int row = i2 >> 6, c = i2 & 63;
    int b = row / 960;
    NK[i2] = node[(size_t)(b * 48 + nidx[row]) * 64 + c];
  } else if (idx < R2 * 192 + 1408) {
    int o = idx - R2 * 192;
    const float* p; int cols; int dsto;
    if (o < 512) { p = W72A; cols = 128; dsto = o; }
    else if (o < 640) { p = W72B; cols = 512; dsto = o; o -= 512; }
    else if (o < 1280) { p = W73A; cols = 320; dsto = o; o -= 640; }
    else { p = W73B; cols = 640; dsto = o; o -= 1280; }
    const float* rowp = p + (size_t)o * cols;
    float s = 0.f;
    for (int j = 0; j < cols; ++j) s += rowp[j];
    rs[dsto] = s;
  }
  blockMinMax(lmn, lmx, sred, slot);
}

// ---------------- K3: quant2A + piecewise c3 minmax (slot4) ----------------
__global__ __launch_bounds__(256) void k_qm4(
    const float* __restrict__ node, const float* __restrict__ edge,
    const float* __restrict__ c2in, const float* __restrict__ NK,
    const int* __restrict__ nidx, const unsigned* __restrict__ slot0,
    unsigned char* __restrict__ Q2A, unsigned* __restrict__ slot4) {
  __shared__ float sred[512];
  int idx0 = blockIdx.x * 256 + threadIdx.x;
  if (idx0 < R2 * 128) {
    const float mn = o2f(slot0[0]), mx = o2f(slot0[1]);
    float invd = 255.f / (mx - mn);
    Q2A[idx0] = (unsigned char)((c2in[idx0] - mn) * invd);
  }
  const int n0 = 12288, n1 = n0 + 245760, n2 = n1 + 245760, total = n2 + 4915200;
  float lmn = 3.4e38f, lmx = -3.4e38f;
  for (int idx = idx0; idx < total; idx += gridDim.x * 256) {
    float v, v2;
    if (idx < n0) { v = node[idx]; v2 = v; }
    else if (idx < n1) { v = edge[idx - n0]; v2 = v; }
    else if (idx < n2) {
      int j = idx - n1; int r = j >> 6, c = j & 63;
      v = c2in[(size_t)r * 128 + 64 + c]; v2 = v;
    } else {
      int j = idx - n2; int bij = j / 1280, t = j - bij * 1280;
      int b = bij / 960;
      size_t base = (size_t)((b * 48 + nidx[bij]) * 20) * 64 + t;
      v = NK[base]; v2 = edge[base];
    }
    lmn = fminf(lmn, fminf(v, v2)); lmx = fmaxf(lmx, fmaxf(v, v2));
  }
  blockMinMax(lmn, lmx, sred, slot4);
}

// ---------------- K4/K7: generic noise-split GEMM (split-K via z) ----------------
__global__ __launch_bounds__(256) void k_nsgemm(
    const unsigned char* __restrict__ Q, int ldq,
    const short* __restrict__ BNp, const short* __restrict__ BWp,
    int KCfull, int c0, int Nfull, int CB,
    float* __restrict__ Z, int accflag) {
  nsgemm_body(Q, ldq, BNp, BWp, KCfull, c0, Nfull, CB, blockIdx.z * CB,
              blockIdx.y * 64, blockIdx.x * 128, Z, accflag);
}

// ---------------- K8: merged P2/P3 noise-split GEMM (z selects half) ----------------
__global__ __launch_bounds__(256) void k_ns_p23(
    const unsigned char* __restrict__ QP2, const unsigned char* __restrict__ QP3,
    const short* __restrict__ BNp, const short* __restrict__ BWp,
    float* __restrict__ P2, float* __restrict__ P3) {
  const int half = blockIdx.z;
  const unsigned char* Q = half ? QP3 : QP2;
  const int ldq = half ? 128 : 192;
  const int c0 = half ? 6 : 0;
  const int CB = half ? 4 : 6;
  float* Z = half ? P3 : P2;
  nsgemm_body(Q, ldq, BNp, BWp, 10, c0, 640, CB, 0,
              blockIdx.y * 64, blockIdx.x * 128, Z, 0);
}

// ---------------- K5: act1 minmax only (slot2) ----------------
__global__ __launch_bounds__(256) void k_act1(const float* __restrict__ z1, const float* __restrict__ rs,
                                              const unsigned* __restrict__ slot0,
                                              unsigned* __restrict__ slot1) {
  __shared__ float sred[512];
  const float mn = o2f(slot0[0]), mx = o2f(slot0[1]);
  int idx = blockIdx.x * 256 + threadIdx.x;
  float lmn = 3.4e38f, lmx = -3.4e38f;
  if (idx < R2 * 512) {
    int o = idx & 511;
    float v = fmaxf(0.f, z1[idx] * (1.f / 255.f) * (mx - mn) + mn * rs[o]);
    lmn = v; lmx = v;
  }
  blockMinMax(lmn, lmx, sred, slot1);
}

// ---------------- K6: quant2B (recompute act from z1) + quant3 ----------------
__global__ __launch_bounds__(256) void k_qq(
    const float* __restrict__ z1, const float* __restrict__ rs,
    const float* __restrict__ node, const float* __restrict__ edge,
    const float* __restrict__ c2in, const float* __restrict__ NK,
    const int* __restrict__ nidx, const unsigned* __restrict__ slot0,
    const unsigned* __restrict__ slot2, const unsigned* __restrict__ slot4,
    unsigned char* __restrict__ Q2B, unsigned char* __restrict__ QP2, unsigned char* __restrict__ QP3) {
  int idx = blockIdx.x * 256 + threadIdx.x;
  if (idx < R2 * 512) {
    const float mn0 = o2f(slot0[0]), mx0 = o2f(slot0[1]);
    const float mn = o2f(slot2[0]), mx = o2f(slot2[1]);
    int o = idx & 511;
    float v = fmaxf(0.f, z1[idx] * (1.f / 255.f) * (mx0 - mn0) + mn0 * rs[o]);
    Q2B[idx] = (unsigned char)((v - mn) * (255.f / (mx - mn)));
    return;
  }
  int j = idx - R2 * 512;
  const int seg = 245760;
  if (j >= 5 * seg) return;
  const float mn = o2f(slot4[0]), mx = o2f(slot4[1]);
  const float invd = 255.f / (mx - mn);
  int s = j / seg; int jj = j - s * seg;
  int r = jj >> 6, c = jj & 63;
  float v; unsigned char* dst;
  if (s == 0)      { v = node[(size_t)(r / 20) * 64 + c];  dst = QP2 + (size_t)r * 192 + c; }
  else if (s == 1) { v = c2in[(size_t)r * 128 + 64 + c];   dst = QP2 + (size_t)r * 192 + 64 + c; }
  else if (s == 2) { v = edge[(size_t)r * 64 + c];         dst = QP2 + (size_t)r * 192 + 128 + c; }
  else if (s == 3) { v = NK[(size_t)r * 64 + c];           dst = QP3 + (size_t)r * 128 + c; }
  else             { v = edge[(size_t)r * 64 + c];         dst = QP3 + (size_t)r * 128 + 64 + c; }
  *dst = (unsigned char)((v - mn) * invd);
}

// ---------------- K9: act2 + minmax3 (slot6) ----------------
__global__ __launch_bounds__(256) void k_act2mm3(
    const float* __restrict__ z2, const float* __restrict__ rs2b,
    const unsigned* __restrict__ slot2, float* __restrict__ two,
    const float* __restrict__ P12, const float* __restrict__ P3,
    const float* __restrict__ rs3a, const int* __restrict__ nidx,
    const unsigned* __restrict__ slot4, unsigned* __restrict__ slot6) {
  __shared__ float p12s[640];
  __shared__ float bias[640];
  __shared__ float sred[512];
  int gid = blockIdx.x * 256 + threadIdx.x;
  if (gid < R2 * 64) {
    const float mn = o2f(slot2[0]), mx = o2f(slot2[1]);
    int row = gid >> 6, c = gid & 63;
    float d = (mx - mn) * (1.f / 255.f);
    float g = z2[(size_t)row * 128 + c] * d + mn * rs2b[c];
    float e = z2[(size_t)row * 128 + 64 + c] * d + mn * rs2b[64 + c];
    two[gid] = (1.f / (1.f + expf(-g))) * tanhf(e);
  }
  const int bij = blockIdx.x;
  const int b = bij / 960;
  const int jp = nidx[bij];
  const size_t p3b = (size_t)((b * 48 + jp) * 20) * 640;
  const float mn2 = o2f(slot4[0]), mx2 = o2f(slot4[1]);
  const float sc2 = (mx2 - mn2) * (1.f / 255.f);
  for (int k = threadIdx.x; k < 640; k += 256) {
    p12s[k] = P12[(size_t)bij * 640 + k];
    bias[k] = mn2 * rs3a[k];
  }
  __syncthreads();
  float lmn = 3.4e38f, lmx = -3.4e38f;
  for (int t = threadIdx.x; t < 20 * 640; t += 256) {
    int knb = t / 640, k = t - knb * 640;
    float v = fmaxf(0.f, (p12s[k] + P3[p3b + t]) * sc2 + bias[k]);
    lmn = fminf(lmn, v); lmx = fmaxf(lmx, v);
  }
  blockMinMax(lmn, lmx, sred, slot6);
}

// ---------------- K10: fused 3-body layer 2 (round-6 schedule, bias LDS) ----------------
__global__ __launch_bounds__(256) void k_mfma_l3b(
    const float* __restrict__ P12, const float* __restrict__ P3,
    const float* __restrict__ rs3a, const float* __restrict__ rs3b,
    const short* __restrict__ BW, const short* __restrict__ BN,
    const int* __restrict__ nidx, const float* __restrict__ mask,
    const unsigned* __restrict__ slotA, const unsigned* __restrict__ slotB,
    float* __restrict__ tsum) {
  __shared__ unsigned char qt[64 * 648];   // 648-byte pad: conflict-free
  __shared__ float bias[640];
  const int tid = threadIdx.x;
  const int s0 = blockIdx.x * 64;
  const float mn2 = o2f(slotA[0]), mx2 = o2f(slotA[1]);
  const float mn3 = o2f(slotB[0]), mx3 = o2f(slotB[1]);
  const float sc2 = (mx2 - mn2) * (1.f / 255.f);
  const float invd3 = 255.f / (mx3 - mn3);
  for (int k = tid; k < 640; k += 256) bias[k] = mn2 * rs3a[k];
  __syncthreads();
  {
    int r = tid >> 2, kq = (tid & 3) * 160;
    int s = s0 + r;
    int bij = s / 20, knb = s - bij * 20, b = bij / 960;
    int p3row = (b * 48 + nidx[bij]) * 20 + knb;
    const float* pa = P12 + (size_t)bij * 640;
    const float* pb = P3 + (size_t)p3row * 640;
    for (int k = kq; k < kq + 160; k += 4) {
      float4 va = *(const float4*)(pa + k);
      float4 vb = *(const float4*)(pb + k);
      float v0 = fmaxf(0.f, (va.x + vb.x) * sc2 + bias[k + 0]);
      float v1 = fmaxf(0.f, (va.y + vb.y) * sc2 + bias[k + 1]);
      float v2 = fmaxf(0.f, (va.z + vb.z) * sc2 + bias[k + 2]);
      float v3 = fmaxf(0.f, (va.w + vb.w) * sc2 + bias[k + 3]);
      unsigned pk = (unsigned)((v0 - mn3) * invd3) | ((unsigned)((v1 - mn3) * invd3) << 8)
                  | ((unsigned)((v2 - mn3) * invd3) << 16) | ((unsigned)((v3 - mn3) * invd3) << 24);
      *(unsigned*)(&qt[(size_t)r * 648 + k]) = pk;
    }
  }
  __syncthreads();
  const int lane = tid & 63, wave = tid >> 6;
  const int wm = wave >> 1, wn = wave & 1;
  const int l15 = lane & 15, l4 = lane >> 4;
  const int nfl[4] = {2 * wn, 2 * wn + 1, 2 * wn + 4, 2 * wn + 5};
  size_t bb[4];
  #pragma unroll
  for (int j = 0; j < 4; ++j) bb[j] = ((size_t)nfl[j] * 160) * 512 + (size_t)lane * 8;
  f4v acc[2][4];
  #pragma unroll
  for (int a = 0; a < 2; ++a)
    #pragma unroll
    for (int b = 0; b < 4; ++b) acc[a][b] = f4v{0.f, 0.f, 0.f, 0.f};
  s8v c0[4], c1[4];
  #pragma unroll
  for (int j = 0; j < 4; ++j) {
    c0[j] = *(const s8v*)(BN + bb[j]);
    c1[j] = *(const s8v*)(BN + bb[j] + 512);
  }
  const unsigned char* qrow0 = &qt[(size_t)(wm * 32 + l15) * 648];
  const unsigned char* qrow1 = qrow0 + 16 * 648;
  for (int c = 0; c < 20; ++c) {
    s8v bwh[4];
    #pragma unroll
    for (int j = 0; j < 4; ++j)
      bwh[j] = *(const s8v*)(BW + (((size_t)nfl[j] * 20 + c) * 2) * 512 + (size_t)lane * 8);
    #pragma unroll
    for (int s = 0; s < 8; ++s) {
      const int kg = c * 8 + s;
      unsigned w0 = *(const unsigned*)(qrow0 + kg * 4);
      unsigned w1 = *(const unsigned*)(qrow1 + kg * 4);
      s8v af0 = expand_mul((w0 >> (l4 * 8)) & 255u);
      s8v af1 = expand_mul((w1 >> (l4 * 8)) & 255u);
      s8v nx[4];
      #pragma unroll
      for (int j = 0; j < 4; ++j)
        nx[j] = *(const s8v*)(BN + bb[j] + (size_t)(kg + 2) * 512);
      #pragma unroll
      for (int j = 0; j < 4; ++j) {
        acc[0][j] = __builtin_amdgcn_mfma_f32_16x16x32_bf16(af0, c0[j], acc[0][j], 0, 0, 0);
        acc[1][j] = __builtin_amdgcn_mfma_f32_16x16x32_bf16(af1, c0[j], acc[1][j], 0, 0, 0);
      }
      #pragma unroll
      for (int j = 0; j < 4; ++j) { c0[j] = c1[j]; c1[j] = nx[j]; }
    }
    {
      const int x = c * 32 + l4 * 8;
      unsigned a0 = *(const unsigned*)(qrow0 + x);
      unsigned a1 = *(const unsigned*)(qrow0 + x + 4);
      s8v aq0 = bytes_to_bf16(a0, a1);
      a0 = *(const unsigned*)(qrow1 + x);
      a1 = *(const unsigned*)(qrow1 + x + 4);
      s8v aq1 = bytes_to_bf16(a0, a1);
      #pragma unroll
      for (int j = 0; j < 4; ++j) {
        acc[0][j] = __builtin_amdgcn_mfma_f32_16x16x32_bf16(aq0, bwh[j], acc[0][j], 0, 0, 0);
        acc[1][j] = __builtin_amdgcn_mfma_f32_16x16x32_bf16(aq1, bwh[j], acc[1][j], 0, 0, 0);
        s8v bwl = *(const s8v*)(BW + ((((size_t)nfl[j] * 20 + c) * 2) + 1) * 512 + (size_t)lane * 8);
        acc[0][j] = __builtin_amdgcn_mfma_f32_16x16x32_bf16(aq0, bwl, acc[0][j], 0, 0, 0);
        acc[1][j] = __builtin_amdgcn_mfma_f32_16x16x32_bf16(aq1, bwl, acc[1][j], 0, 0, 0);
      }
    }
  }
  const float d3 = (mx3 - mn3) * (1.f / 255.f);
  float rg[2], re[2];
  #pragma unroll
  for (int j = 0; j < 2; ++j) {
    int gcol = (2 * wn + j) * 16 + l15;
    rg[j] = mn3 * rs3b[gcol];
    re[j] = mn3 * rs3b[64 + gcol];
  }
  #pragma unroll
  for (int mf = 0; mf < 2; ++mf) {
    #pragma unroll
    for (int r = 0; r < 4; ++r) {
      int s = s0 + wm * 32 + mf * 16 + l4 * 4 + r;
      int bij = s / 20, knb = s - bij * 20, b = bij / 960;
      int p3row = (b * 48 + nidx[bij]) * 20 + knb;
      float mk = mask[p3row];
      #pragma unroll
      for (int j = 0; j < 2; ++j) {
        float g = acc[mf][j][r] * d3 + rg[j];
        float e = acc[mf][j + 2][r] * d3 + re[j];
        float val = (1.f / (1.f + expf(-g))) * tanhf(e) * mk;
        atomicAdd(&tsum[(size_t)bij * 64 + (2 * wn + j) * 16 + l15], val);
      }
    }
  }
}

// ---------------- K11/K12: BN stats + final ----------------
__global__ __launch_bounds__(256) void k_bnstats2(const float* __restrict__ two, const float* __restrict__ tsum,
                                                  float* __restrict__ bn) {
  __shared__ float ss[512];
  const float* x = blockIdx.y ? tsum : two;
  float* mout = bn + (blockIdx.y ? 128 : 0);
  float* vout = mout + 64;
  int c = blockIdx.x, t = threadIdx.x;
  float s = 0.f, q = 0.f;
  for (int r = t; r < R2; r += 256) { float v = x[(size_t)r * 64 + c]; s += v; q += v * v; }
  ss[t] = s; ss[256 + t] = q;
  __syncthreads();
  for (int st = 128; st > 0; st >>= 1) {
    if (t < st) { ss[t] += ss[t + st]; ss[256 + t] += ss[256 + t + st]; }
    __syncthreads();
  }
  if (t == 0) { float m = ss[0] / (float)R2; mout[c] = m; vout[c] = ss[256] / (float)R2 - m * m; }
}

__global__ __launch_bounds__(256) void k_final(const float* __restrict__ edge, const float* __restrict__ two,
                                               const float* __restrict__ tsum, const float* __restrict__ bn,
                                               const float* __restrict__ g2, const float* __restrict__ b2,
                                               const float* __restrict__ g3, const float* __restrict__ b3,
                                               float* __restrict__ out) {
  int idx = blockIdx.x * 256 + threadIdx.x;
  if (idx >= R2 * 64) return;
  int c = idx & 63;
  float t2 = (two[idx] - bn[c]) / sqrtf(bn[64 + c] + 1e-5f) * g2[c] + b2[c];
  float t3 = (tsum[idx] - bn[128 + c]) / sqrtf(bn[192 + c] + 1e-5f) * g3[c] + b3[c];
  out[idx] = fmaxf(0.f, edge[idx] + t2 + t3);
}

// ---------------- host launcher ----------------
extern "C" void kernel_launch(void* const* d_in, const int* in_sizes, int n_in,
                              void* d_out, int out_size, void* d_ws, size_t ws_size,
                              hipStream_t stream) {
  (void)in_sizes; (void)n_in; (void)out_size; (void)ws_size;
  const float* node   = (const float*)d_in[0];
  const float* edge   = (const float*)d_in[1];
  const float* mask   = (const float*)d_in[2];
  const float* c_two  = (const float*)d_in[3];
  const float* c_two2 = (const float*)d_in[4];
  const float* c_three  = (const float*)d_in[5];
  const float* c_three2 = (const float*)d_in[6];
  const float* bn2g = (const float*)d_in[7];
  const float* bn2b = (const float*)d_in[8];
  const float* bn3g = (const float*)d_in[9];
  const float* bn3b = (const float*)d_in[10];
  const int*   nidx = (const int*)d_in[11];
  float* ws = (float*)d_ws;
  unsigned* slots = (unsigned*)(ws + OFF_SLOT);
  float* out = (float*)d_out;
  short* BN2A = (short*)(ws + OFF_BN2A); short* BW2A = (short*)(ws + OFF_BW2A);
  short* BN2B = (short*)(ws + OFF_BN2B); short* BW2B = (short*)(ws + OFF_BW2B);
  short* BN3A = (short*)(ws + OFF_BN3A); short* BW3A = (short*)(ws + OFF_BW3A);
  short* BN3B = (short*)(ws + OFF_BN3B); short* BW3B = (short*)(ws + OFF_BW3B);
  unsigned char* Q2A = (unsigned char*)(ws + OFF_Q2A);
  unsigned char* Q2B = (unsigned char*)(ws + OFF_Q2B);
  unsigned char* QP2 = (unsigned char*)(ws + OFF_QP2);
  unsigned char* QP3 = (unsigned char*)(ws + OFF_QP3);
  float* RS = ws + OFF_RS;

  // K1: init + expanded weights (uniform noise-split)
  k_prep<<<7680, 256, 0, stream>>>(c_two, c_two2, c_three, c_three2,
                                   BN2A, BW2A, BN2B, BW2B, BN3A, BW3A, BN3B, BW3B,
                                   ws + OFF_W72A, ws + OFF_W72B, ws + OFF_W73A, ws + OFF_W73B,
                                   ws + OFF_Z1, ws + OFF_Z2, ws + OFF_TSUM, slots);
  // K2: build c2in/NK + rowsums + slot0
  k_build2<<<2886, 256, 0, stream>>>(node, mask, nidx, ws + OFF_C2IN, ws + OFF_NK,
                                     ws + OFF_W72A, ws + OFF_W72B, ws + OFF_W73A, ws + OFF_W73B,
                                     RS, slots + 0);
  // K3: quant2A + 3-body minmax (slot4)
  k_qm4<<<2048, 256, 0, stream>>>(node, edge, ws + OFF_C2IN, ws + OFF_NK, nidx, slots + 0,
                                  Q2A, slots + 4);
  // K4: 2-body layer 1 (noise-split, z=2)
  k_nsgemm<<<dim3(4, 60, 2), 256, 0, stream>>>(Q2A, 128, BN2A, BW2A, 4, 0, 512, 2, ws + OFF_Z1, 3);
  // K5: act1 minmax (slot2)
  k_act1<<<7680, 256, 0, stream>>>(ws + OFF_Z1, RS, slots + 0, slots + 2);
  // K6: quant2B (from z1) + quant3
  k_qq<<<12480, 256, 0, stream>>>(ws + OFF_Z1, RS, node, edge, ws + OFF_C2IN, ws + OFF_NK,
                                  nidx, slots + 0, slots + 2, slots + 4, Q2B, QP2, QP3);
  // K7: 2-body layer 2 (z=8 -> 480 blocks)
  k_nsgemm<<<dim3(1, 60, 8), 256, 0, stream>>>(Q2B, 512, BN2B, BW2B, 16, 0, 128, 2, ws + OFF_Z2, 3);
  // K8: merged P2/P3 (600 blocks, z selects half)
  k_ns_p23<<<dim3(5, 60, 2), 256, 0, stream>>>(QP2, QP3, BN3A, BW3A, ws + OFF_P2, ws + OFF_P3);
  // K9: act2 + minmax3 (slot6)
  k_act2mm3<<<3840, 256, 0, stream>>>(ws + OFF_Z2, RS + 512, slots + 2, ws + OFF_TWO,
                                      ws + OFF_P2, ws + OFF_P3, RS + 640, nidx, slots + 4, slots + 6);
  // K10: fused 3-body layer 2 (round-6 schedule, bias LDS)
  k_mfma_l3b<<<1200, 256, 0, stream>>>(ws + OFF_P2, ws + OFF_P3, RS + 640, RS + 1280,
                                       BW3B, BN3B, nidx, mask, slots + 4, slots + 6, ws + OFF_TSUM);
  // K11/K12
  k_bnstats2<<<dim3(64, 2), 256, 0, stream>>>(ws + OFF_TWO, ws + OFF_TSUM, ws + OFF_BN);
  k_final<<<960, 256, 0, stream>>>(edge, ws + OFF_TWO, ws + OFF_TSUM, ws + OFF_BN,
                                   bn2g, bn2b, bn3g, bn3b, out);
}